// Round 2
// baseline (7636.239 us; speedup 1.0000x reference)
//
#include <hip/hip_runtime.h>
#include <hip/hip_bf16.h>

#define NN 16384
#define NE 65536
#define NESL (NE + NN)
#define NG 64

typedef __hip_bfloat16 bf16;

__device__ __forceinline__ float toF(float v) { return v; }
__device__ __forceinline__ float toF(bf16 v) { return __bfloat162float(v); }
__device__ __forceinline__ void stO(float* p, float v) { *p = v; }
__device__ __forceinline__ void stO(bf16* p, float v) { *p = __float2bfloat16(v); }

// ---------------- utility: zero fill ----------------
__global__ void k_zero(float* a, int n) {
  int i = blockIdx.x * blockDim.x + threadIdx.x;
  if (i < n) a[i] = 0.0f;
}
__global__ void k_zero2(int* a, int* b, int n) {
  int i = blockIdx.x * blockDim.x + threadIdx.x;
  if (i < n) { a[i] = 0; b[i] = 0; }
}

// ---------------- graph preprocessing ----------------

__global__ void k_ranges(const int* __restrict__ batch, int* __restrict__ R,
                         float* __restrict__ cnt) {
  int g = threadIdx.x;
  if (g <= NG) {
    int lo = 0, hi = NN;
    while (lo < hi) { int mid = (lo + hi) >> 1; if (batch[mid] < g) lo = mid + 1; else hi = mid; }
    R[g] = lo;
  }
  __syncthreads();
  if (g < NG) cnt[g] = fmaxf((float)(R[g + 1] - R[g]), 1.0f);
}

__global__ void k_deg(const int* __restrict__ dst, int* __restrict__ deg) {
  int e = blockIdx.x * blockDim.x + threadIdx.x;
  if (e < NE) atomicAdd(deg + dst[e], 1);
}

__global__ void k_dis(const int* __restrict__ deg, float* __restrict__ dis) {
  int n = blockIdx.x * blockDim.x + threadIdx.x;
  if (n < NN) { int d = deg[n]; dis[n] = d > 0 ? 1.0f / sqrtf((float)d) : 0.0f; }
}

__global__ void k_norm(const int* __restrict__ src, const int* __restrict__ dst,
                       const float* __restrict__ dis, float* __restrict__ normv) {
  int e = blockIdx.x * blockDim.x + threadIdx.x;
  if (e < NE) normv[e] = dis[src[e]] * dis[dst[e]];
}

// exclusive scan of (deg[n]+1) -> rowptr[NN+1]; NN = 1024*16
__global__ void k_scan(const int* __restrict__ deg, int* __restrict__ rowptr) {
  __shared__ int sums[1024];
  int tid = threadIdx.x;
  int base = tid * 16;
  int loc[16];
  int run = 0;
#pragma unroll
  for (int i = 0; i < 16; i++) { run += deg[base + i] + 1; loc[i] = run; }
  sums[tid] = run;
  __syncthreads();
  for (int off = 1; off < 1024; off <<= 1) {
    int v = sums[tid];
    int u = (tid >= off) ? sums[tid - off] : 0;
    __syncthreads();
    sums[tid] = v + u;
    __syncthreads();
  }
  int offset = (tid > 0) ? sums[tid - 1] : 0;
  if (tid == 0) rowptr[0] = 0;
#pragma unroll
  for (int i = 0; i < 16; i++) rowptr[base + i + 1] = loc[i] + offset;
}

__global__ void k_fill(const int* __restrict__ src, const int* __restrict__ dst,
                       const int* __restrict__ rowptr, int* __restrict__ fill,
                       int* __restrict__ eidx) {
  int e = blockIdx.x * blockDim.x + threadIdx.x;
  if (e >= NESL) return;
  int d = e < NE ? dst[e] : e - NE;
  int pos = rowptr[d] + atomicAdd(fill + d, 1);
  eidx[pos] = e;
}

// ---------------- GEMM (row-major, C = A@B), A: N x K (TA), B: K x M f32, C: N x M (TC)
template <int BM, int BN, int TM, int TN, typename TA, typename TC>
__global__ void gemm_nn(const TA* __restrict__ A, const float* __restrict__ B,
                        TC* __restrict__ C, int N, int K, int M) {
  constexpr int BK = 16;
  constexpr int NT = (BM / TM) * (BN / TN);  // 256
  __shared__ float As[BK][BM + 4];
  __shared__ float Bs[BK][BN + 4];
  const int tid = threadIdx.x;
  const int tx = tid % (BN / TN);
  const int ty = tid / (BN / TN);
  const int row0 = blockIdx.y * BM;
  const int col0 = blockIdx.x * BN;
  float acc[TM][TN] = {};
  for (int k0 = 0; k0 < K; k0 += BK) {
    for (int i = tid; i < BM * BK; i += NT) {
      int m = i / BK, k = i % BK;
      As[k][m] = toF(A[(size_t)(row0 + m) * K + k0 + k]);
    }
    for (int i = tid; i < BK * BN; i += NT) {
      int k = i / BN, n = i % BN;
      Bs[k][n] = B[(size_t)(k0 + k) * M + col0 + n];
    }
    __syncthreads();
#pragma unroll
    for (int k = 0; k < BK; ++k) {
      float a[TM], b[TN];
#pragma unroll
      for (int i = 0; i < TM; i++) a[i] = As[k][ty * TM + i];
#pragma unroll
      for (int j = 0; j < TN; j++) b[j] = Bs[k][tx * TN + j];
#pragma unroll
      for (int i = 0; i < TM; i++)
#pragma unroll
        for (int j = 0; j < TN; j++) acc[i][j] += a[i] * b[j];
    }
    __syncthreads();
  }
#pragma unroll
  for (int i = 0; i < TM; i++) {
    size_t r = row0 + ty * TM + i;
#pragma unroll
    for (int j = 0; j < TN; j++) stO(&C[r * M + col0 + tx * TN + j], acc[i][j]);
  }
}

// ---------------- GAT attention ----------------

__device__ __forceinline__ unsigned enc_f32(float f) {
  unsigned u = __float_as_uint(f);
  return (u & 0x80000000u) ? ~u : (u | 0x80000000u);
}
__device__ __forceinline__ float dec_f32(unsigned u) {
  return (u & 0x80000000u) ? __uint_as_float(u & 0x7fffffffu) : __uint_as_float(~u);
}

// GAT1 is rank-1 (input feature dim == 1): logits computed analytically.
__global__ void k_logits1(const float* __restrict__ x, const float* __restrict__ wl,
                          const float* __restrict__ wr, const float* __restrict__ att,
                          const int* __restrict__ src, const int* __restrict__ dst,
                          float* __restrict__ el, unsigned* __restrict__ menc) {
  int e = blockIdx.x * (blockDim.x >> 6) + (threadIdx.x >> 6);
  if (e >= NESL) return;
  int lane = threadIdx.x & 63;
  int s = e < NE ? src[e] : e - NE;
  int d = e < NE ? dst[e] : e - NE;
  float v = x[s] * wl[lane] + x[d] * wr[lane];
  v = v > 0.0f ? v : 0.2f * v;
  float acc = att[lane] * v;
#pragma unroll
  for (int off = 32; off; off >>= 1) acc += __shfl_xor(acc, off);
  if (lane == 0) {
    el[e] = acc;
    atomicMax(menc + d, enc_f32(acc));
  }
}

template <int FO, typename XT>
__global__ void k_logits(const XT* __restrict__ xl, const XT* __restrict__ xr,
                         const float* __restrict__ att, const int* __restrict__ src,
                         const int* __restrict__ dst, float* __restrict__ el,
                         unsigned* __restrict__ menc) {
  int e = blockIdx.x * (blockDim.x >> 6) + (threadIdx.x >> 6);
  if (e >= NESL) return;
  int lane = threadIdx.x & 63;
  int s = e < NE ? src[e] : e - NE;
  int d = e < NE ? dst[e] : e - NE;
  float acc = 0.0f;
  for (int f = lane; f < FO; f += 64) {
    float v = toF(xl[(size_t)s * FO + f]) + toF(xr[(size_t)d * FO + f]);
    v = v > 0.0f ? v : 0.2f * v;
    acc += att[f] * v;
  }
#pragma unroll
  for (int off = 32; off; off >>= 1) acc += __shfl_xor(acc, off);
  if (lane == 0) {
    el[e] = acc;
    atomicMax(menc + d, enc_f32(acc));
  }
}

__global__ void k_expsum(const float* __restrict__ el, const int* __restrict__ dst,
                         const unsigned* __restrict__ menc, float* __restrict__ p,
                         float* __restrict__ ssum) {
  int e = blockIdx.x * blockDim.x + threadIdx.x;
  if (e >= NESL) return;
  int d = e < NE ? dst[e] : e - NE;
  float m = dec_f32(menc[d]);
  float pe = expf(el[e] - m);
  p[e] = pe;
  atomicAdd(ssum + d, pe);
}

// GAT1 aggregation: out[n,f] = elu(wl[f]*(sum_e a_e x[src]) + b[f])
__global__ void k_agg1(const float* __restrict__ x, const float* __restrict__ p,
                       const float* __restrict__ ssum, const int* __restrict__ rowptr,
                       const int* __restrict__ eidx, const int* __restrict__ src,
                       const float* __restrict__ wl, const float* __restrict__ bias,
                       float* __restrict__ out) {
  int node = blockIdx.x * (blockDim.x >> 6) + (threadIdx.x >> 6);
  if (node >= NN) return;
  int lane = threadIdx.x & 63;
  int beg = rowptr[node], end = rowptr[node + 1];
  float acc = 0.0f;
  for (int k = beg + lane; k < end; k += 64) {
    int e = eidx[k];
    int s = e < NE ? src[e] : e - NE;
    acc += p[e] * x[s];
  }
#pragma unroll
  for (int off = 32; off; off >>= 1) acc += __shfl_xor(acc, off);
  float inv = 1.0f / (ssum[node] + 1e-16f);
  float o = acc * inv * wl[lane] + bias[lane];
  out[(size_t)node * 64 + lane] = o > 0.0f ? o : expf(o) - 1.0f;
}

// FO >= 256: one block per (node, 256-channel chunk); fused bias + elu
template <typename XT, typename OT>
__global__ void k_gat_agg_big(const XT* __restrict__ xl, const float* __restrict__ p,
                              const float* __restrict__ ssum, const int* __restrict__ rowptr,
                              const int* __restrict__ eidx, const int* __restrict__ src,
                              int FO, const float* __restrict__ bias, OT* __restrict__ out) {
  int node = blockIdx.x;
  int c = blockIdx.y * 256 + threadIdx.x;
  float inv = 1.0f / (ssum[node] + 1e-16f);
  float acc = 0.0f;
  int beg = rowptr[node], end = rowptr[node + 1];
  for (int k = beg; k < end; k++) {
    int e = eidx[k];
    int s = e < NE ? src[e] : e - NE;
    acc += p[e] * inv * toF(xl[(size_t)s * FO + c]);
  }
  acc += bias[c];
  stO(&out[(size_t)node * FO + c], acc > 0.0f ? acc : expf(acc) - 1.0f);
}

// ---------------- ARMA aggregation (fused add + relu; elu(relu)=relu) ----------------

__global__ void k_arma_agg_big(const float* __restrict__ t, const float* __restrict__ normv,
                               const int* __restrict__ rowptr, const int* __restrict__ eidx,
                               const int* __restrict__ src, int C,
                               const float* __restrict__ xwr, const float* __restrict__ bias,
                               float* __restrict__ out) {
  int node = blockIdx.x;
  int c = blockIdx.y * 256 + threadIdx.x;
  float acc = 0.0f;
  int beg = rowptr[node], end = rowptr[node + 1];
  for (int k = beg; k < end; k++) {
    int e = eidx[k];
    if (e >= NE) continue;  // no self loops in ARMA
    acc += normv[e] * t[(size_t)src[e] * C + c];
  }
  acc += xwr[(size_t)node * C + c] + bias[c];
  out[(size_t)node * C + c] = fmaxf(acc, 0.0f);
}

__global__ void k_arma_agg64(const float* __restrict__ t, const float* __restrict__ normv,
                             const int* __restrict__ rowptr, const int* __restrict__ eidx,
                             const int* __restrict__ src, const float* __restrict__ xwr,
                             const float* __restrict__ bias, float* __restrict__ out) {
  int node = blockIdx.x * (blockDim.x >> 6) + (threadIdx.x >> 6);
  if (node >= NN) return;
  int lane = threadIdx.x & 63;
  float acc = 0.0f;
  int beg = rowptr[node], end = rowptr[node + 1];
  for (int k = beg; k < end; k++) {
    int e = eidx[k];
    if (e >= NE) continue;
    acc += normv[e] * t[(size_t)src[e] * 64 + lane];
  }
  acc += xwr[(size_t)node * 64 + lane] + bias[lane];
  out[(size_t)node * 64 + lane] = fmaxf(acc, 0.0f);
}

// ---------------- GraphNorm ----------------

template <typename T>
__global__ void k_gn_stats(const T* __restrict__ x, const int* __restrict__ R, int C,
                           float* __restrict__ s1, float* __restrict__ s2) {
  int g = blockIdx.x;
  int c = blockIdx.y * blockDim.x + threadIdx.x;
  int beg = R[g], end = R[g + 1];
  float a = 0.0f, b = 0.0f;
  for (int n = beg; n < end; n++) {
    float v = toF(x[(size_t)n * C + c]);
    a += v;
    b += v * v;
  }
  s1[g * C + c] = a;
  s2[g * C + c] = b;
}

template <typename T>
__global__ void k_gn_apply(T* __restrict__ x, const int* __restrict__ batch,
                           const float* __restrict__ cnt, const float* __restrict__ s1,
                           const float* __restrict__ s2, const float* __restrict__ w,
                           const float* __restrict__ b, const float* __restrict__ ms, int C,
                           size_t total) {
  size_t i = (size_t)blockIdx.x * blockDim.x + threadIdx.x;
  if (i >= total) return;
  int n = (int)(i / C);
  int c = (int)(i % C);
  int g = batch[n];
  float ct = cnt[g];
  float mean = s1[g * C + c] / ct;
  float mm = mean * ms[c];
  float var = s2[g * C + c] / ct - 2.0f * mm * mean + mm * mm;
  float v = toF(x[i]);
  stO(&x[i], (v - mm) * (1.0f / sqrtf(var + 1e-5f)) * w[c] + b[c]);
}

// ---------------- pooling + final linear ----------------

__global__ void k_pool(const float* __restrict__ h, const int* __restrict__ R,
                       const float* __restrict__ cnt, const float* __restrict__ lw,
                       const float* __restrict__ lb, float* __restrict__ out) {
  int g = blockIdx.x;
  int c = threadIdx.x;  // 64 threads
  int beg = R[g], end = R[g + 1];
  float mx = -INFINITY, sm = 0.0f;
  for (int n = beg; n < end; n++) {
    float v = h[(size_t)n * 64 + c];
    mx = fmaxf(mx, v);
    sm += v;
  }
  __shared__ float feat[192];
  feat[c] = mx;
  feat[64 + c] = sm / cnt[g];
  feat[128 + c] = sm;
  __syncthreads();
  if (c < 2) {
    float acc = lb[c];
    for (int j = 0; j < 192; j++) acc += feat[j] * lw[j * 2 + c];
    out[g * 2 + c] = acc;
  }
}

// ---------------- launch ----------------

extern "C" void kernel_launch(void* const* d_in, const int* in_sizes, int n_in,
                              void* d_out, int out_size, void* d_ws, size_t ws_size,
                              hipStream_t stream) {
  const float* x = (const float*)d_in[0];
  const int* ei = (const int*)d_in[1];
  const int* batch = (const int*)d_in[2];
  const float* g1wl = (const float*)d_in[3];
  const float* g1wr = (const float*)d_in[4];
  const float* g1att = (const float*)d_in[5];
  const float* g1b = (const float*)d_in[6];
  const float* g2wl = (const float*)d_in[7];
  const float* g2wr = (const float*)d_in[8];
  const float* g2att = (const float*)d_in[9];
  const float* g2b = (const float*)d_in[10];
  const float* g3wl = (const float*)d_in[11];
  const float* g3wr = (const float*)d_in[12];
  const float* g3att = (const float*)d_in[13];
  const float* g3b = (const float*)d_in[14];
  const float* gn1w = (const float*)d_in[15];
  const float* gn1b = (const float*)d_in[16];
  const float* gn1ms = (const float*)d_in[17];
  const float* gn2w = (const float*)d_in[18];
  const float* gn2b = (const float*)d_in[19];
  const float* gn2ms = (const float*)d_in[20];
  const float* gn3w = (const float*)d_in[21];
  const float* gn3b = (const float*)d_in[22];
  const float* gn3ms = (const float*)d_in[23];
  const float* gn4w = (const float*)d_in[24];
  const float* gn4b = (const float*)d_in[25];
  const float* gn4ms = (const float*)d_in[26];
  const float* gn5w = (const float*)d_in[27];
  const float* gn5b = (const float*)d_in[28];
  const float* gn5ms = (const float*)d_in[29];
  const float* a1wi = (const float*)d_in[30];
  const float* a1wr = (const float*)d_in[31];
  const float* a1b = (const float*)d_in[32];
  const float* a2wi = (const float*)d_in[33];
  const float* a2wr = (const float*)d_in[34];
  const float* a2b = (const float*)d_in[35];
  const float* linw = (const float*)d_in[36];
  const float* linb = (const float*)d_in[37];
  const int* srcp = ei;
  const int* dstp = ei + NE;
  float* out = (float*)d_out;

  float* ws = (float*)d_ws;
  size_t o = 0;
  auto alloc = [&](size_t nfloats) { float* p = ws + o; o += nfloats; return p; };
  // bf16 regions (NN x 2048 bf16 each = NN*1024 floats)
  bf16* BIGbf0 = (bf16*)alloc((size_t)NN * 1024);  // xl3; later reused (fp32) as h4
  bf16* BIGbf1 = (bf16*)alloc((size_t)NN * 1024);  // xr3 -> h3
  float* B0 = alloc((size_t)NN * 512);             // xl2 -> t1
  float* B1 = alloc((size_t)NN * 512);             // xr2 -> h2 -> xwr1
  float* h1 = alloc((size_t)NN * 64);
  float* S0 = alloc((size_t)NN * 64);  // t2
  float* S1 = alloc((size_t)NN * 64);  // xwr2
  float* S2 = alloc((size_t)NN * 64);  // h5
  float* el = alloc(NESL);
  float* pbuf = alloc(NESL);
  float* ssum = alloc(NN);
  float* dis = alloc(NN);
  float* normv = alloc(NE);
  float* cnt = alloc(NG);
  float* s1 = alloc(NG * 2048);
  float* s2 = alloc(NG * 2048);
  unsigned* menc = (unsigned*)alloc(NN);
  int* deg = (int*)alloc(NN);
  int* rowptr = (int*)alloc(NN + 1);
  int* fill = (int*)alloc(NN);
  int* eidx = (int*)alloc(NESL);
  int* R = (int*)alloc(72);
  float* h4 = (float*)BIGbf0;  // fp32 NN x 512 reuse (after GAT3 done)

  // ---- preprocessing ----
  k_zero2<<<NN / 256, 256, 0, stream>>>(deg, fill, NN);
  k_ranges<<<1, 128, 0, stream>>>(batch, R, cnt);
  k_deg<<<NE / 256, 256, 0, stream>>>(dstp, deg);
  k_scan<<<1, 1024, 0, stream>>>(deg, rowptr);
  k_fill<<<(NESL + 255) / 256, 256, 0, stream>>>(srcp, dstp, rowptr, fill, eidx);
  k_dis<<<NN / 256, 256, 0, stream>>>(deg, dis);
  k_norm<<<NE / 256, 256, 0, stream>>>(srcp, dstp, dis, normv);

  // ---- GAT1 (1 -> 64, rank-1) ----
  k_zero<<<NN / 256, 256, 0, stream>>>((float*)menc, NN);
  k_zero<<<NN / 256, 256, 0, stream>>>(ssum, NN);
  k_logits1<<<(NESL + 3) / 4, 256, 0, stream>>>(x, g1wl, g1wr, g1att, srcp, dstp, el, menc);
  k_expsum<<<(NESL + 255) / 256, 256, 0, stream>>>(el, dstp, menc, pbuf, ssum);
  k_agg1<<<NN / 4, 256, 0, stream>>>(x, pbuf, ssum, rowptr, eidx, srcp, g1wl, g1b, h1);
  k_gn_stats<float><<<dim3(NG, 1), 64, 0, stream>>>(h1, R, 64, s1, s2);
  k_gn_apply<float><<<(NN * 64 + 255) / 256, 256, 0, stream>>>(h1, batch, cnt, s1, s2, gn1w,
                                                               gn1b, gn1ms, 64, (size_t)NN * 64);

  // ---- GAT2 (64 -> 512) ----
  gemm_nn<128, 128, 8, 8, float, float><<<dim3(4, 128), 256, 0, stream>>>(h1, g2wl, B0, NN, 64, 512);
  gemm_nn<128, 128, 8, 8, float, float><<<dim3(4, 128), 256, 0, stream>>>(h1, g2wr, B1, NN, 64, 512);
  k_zero<<<NN / 256, 256, 0, stream>>>((float*)menc, NN);
  k_zero<<<NN / 256, 256, 0, stream>>>(ssum, NN);
  k_logits<512, float><<<(NESL + 3) / 4, 256, 0, stream>>>(B0, B1, g2att, srcp, dstp, el, menc);
  k_expsum<<<(NESL + 255) / 256, 256, 0, stream>>>(el, dstp, menc, pbuf, ssum);
  k_gat_agg_big<float, float><<<dim3(NN, 2), 256, 0, stream>>>(B0, pbuf, ssum, rowptr, eidx,
                                                               srcp, 512, g2b, B1);
  k_gn_stats<float><<<dim3(NG, 2), 256, 0, stream>>>(B1, R, 512, s1, s2);
  k_gn_apply<float><<<(NN * 512 + 255) / 256, 256, 0, stream>>>(B1, batch, cnt, s1, s2, gn2w,
                                                                gn2b, gn2ms, 512, (size_t)NN * 512);

  // ---- GAT3 (512 -> 2048, bf16 storage) ----
  gemm_nn<128, 128, 8, 8, float, bf16><<<dim3(16, 128), 256, 0, stream>>>(B1, g3wl, BIGbf0, NN, 512, 2048);
  gemm_nn<128, 128, 8, 8, float, bf16><<<dim3(16, 128), 256, 0, stream>>>(B1, g3wr, BIGbf1, NN, 512, 2048);
  k_zero<<<NN / 256, 256, 0, stream>>>((float*)menc, NN);
  k_zero<<<NN / 256, 256, 0, stream>>>(ssum, NN);
  k_logits<2048, bf16><<<(NESL + 3) / 4, 256, 0, stream>>>(BIGbf0, BIGbf1, g3att, srcp, dstp, el, menc);
  k_expsum<<<(NESL + 255) / 256, 256, 0, stream>>>(el, dstp, menc, pbuf, ssum);
  k_gat_agg_big<bf16, bf16><<<dim3(NN, 8), 256, 0, stream>>>(BIGbf0, pbuf, ssum, rowptr, eidx,
                                                             srcp, 2048, g3b, BIGbf1);
  k_gn_stats<bf16><<<dim3(NG, 8), 256, 0, stream>>>(BIGbf1, R, 2048, s1, s2);
  k_gn_apply<bf16><<<(size_t)NN * 2048 / 256, 256, 0, stream>>>(BIGbf1, batch, cnt, s1, s2, gn3w,
                                                                gn3b, gn3ms, 2048, (size_t)NN * 2048);

  // ---- ARMA1 (2048 -> 512) ----
  gemm_nn<128, 128, 8, 8, bf16, float><<<dim3(4, 128), 256, 0, stream>>>(BIGbf1, a1wi, B0, NN, 2048, 512);
  gemm_nn<128, 128, 8, 8, bf16, float><<<dim3(4, 128), 256, 0, stream>>>(BIGbf1, a1wr, B1, NN, 2048, 512);
  k_arma_agg_big<<<dim3(NN, 2), 256, 0, stream>>>(B0, normv, rowptr, eidx, srcp, 512, B1, a1b, h4);
  k_gn_stats<float><<<dim3(NG, 2), 256, 0, stream>>>(h4, R, 512, s1, s2);
  k_gn_apply<float><<<(NN * 512 + 255) / 256, 256, 0, stream>>>(h4, batch, cnt, s1, s2, gn4w,
                                                                gn4b, gn4ms, 512, (size_t)NN * 512);

  // ---- ARMA2 (512 -> 64) ----
  gemm_nn<64, 64, 4, 4, float, float><<<dim3(1, 256), 256, 0, stream>>>(h4, a2wi, S0, NN, 512, 64);
  gemm_nn<64, 64, 4, 4, float, float><<<dim3(1, 256), 256, 0, stream>>>(h4, a2wr, S1, NN, 512, 64);
  k_arma_agg64<<<NN / 4, 256, 0, stream>>>(S0, normv, rowptr, eidx, srcp, S1, a2b, S2);
  k_gn_stats<float><<<dim3(NG, 1), 64, 0, stream>>>(S2, R, 64, s1, s2);
  k_gn_apply<float><<<(NN * 64 + 255) / 256, 256, 0, stream>>>(S2, batch, cnt, s1, s2, gn5w,
                                                               gn5b, gn5ms, 64, (size_t)NN * 64);

  // ---- pooling + linear ----
  k_pool<<<NG, 64, 0, stream>>>(S2, R, cnt, linw, linb, out);
}

// Round 3
// 1992.800 us; speedup vs baseline: 3.8319x; 3.8319x over previous
//
#include <hip/hip_runtime.h>
#include <hip/hip_bf16.h>

#define NN 16384
#define NE 65536
#define NESL (NE + NN)
#define NG 64

typedef __hip_bfloat16 bf16;
typedef __attribute__((ext_vector_type(8))) short short8v;
typedef __attribute__((ext_vector_type(4))) float f32x4;

__device__ __forceinline__ float toF(float v) { return v; }
__device__ __forceinline__ float toF(bf16 v) { return __bfloat162float(v); }
__device__ __forceinline__ void stO(float* p, float v) { *p = v; }
__device__ __forceinline__ void stO(bf16* p, float v) { *p = __float2bfloat16(v); }
__device__ __forceinline__ short bfbits(float v) {
  bf16 h = __float2bfloat16(v);
  return *(short*)&h;
}

// ---------------- utility: zero fill ----------------
__global__ void k_zero(float* a, int n) {
  int i = blockIdx.x * blockDim.x + threadIdx.x;
  if (i < n) a[i] = 0.0f;
}
__global__ void k_zero2(int* a, int* b, int n) {
  int i = blockIdx.x * blockDim.x + threadIdx.x;
  if (i < n) { a[i] = 0; b[i] = 0; }
}

// ---------------- graph preprocessing ----------------

__global__ void k_ranges(const int* __restrict__ batch, int* __restrict__ R,
                         float* __restrict__ cnt) {
  int g = threadIdx.x;
  if (g <= NG) {
    int lo = 0, hi = NN;
    while (lo < hi) { int mid = (lo + hi) >> 1; if (batch[mid] < g) lo = mid + 1; else hi = mid; }
    R[g] = lo;
  }
  __syncthreads();
  if (g < NG) cnt[g] = fmaxf((float)(R[g + 1] - R[g]), 1.0f);
}

__global__ void k_deg(const int* __restrict__ dst, int* __restrict__ deg) {
  int e = blockIdx.x * blockDim.x + threadIdx.x;
  if (e < NE) atomicAdd(deg + dst[e], 1);
}

__global__ void k_dis(const int* __restrict__ deg, float* __restrict__ dis) {
  int n = blockIdx.x * blockDim.x + threadIdx.x;
  if (n < NN) { int d = deg[n]; dis[n] = d > 0 ? 1.0f / sqrtf((float)d) : 0.0f; }
}

__global__ void k_norm(const int* __restrict__ src, const int* __restrict__ dst,
                       const float* __restrict__ dis, float* __restrict__ normv) {
  int e = blockIdx.x * blockDim.x + threadIdx.x;
  if (e < NE) normv[e] = dis[src[e]] * dis[dst[e]];
}

// exclusive scan of (deg[n]+1) -> rowptr[NN+1]; NN = 1024*16
__global__ void k_scan(const int* __restrict__ deg, int* __restrict__ rowptr) {
  __shared__ int sums[1024];
  int tid = threadIdx.x;
  int base = tid * 16;
  int loc[16];
  int run = 0;
#pragma unroll
  for (int i = 0; i < 16; i++) { run += deg[base + i] + 1; loc[i] = run; }
  sums[tid] = run;
  __syncthreads();
  for (int off = 1; off < 1024; off <<= 1) {
    int v = sums[tid];
    int u = (tid >= off) ? sums[tid - off] : 0;
    __syncthreads();
    sums[tid] = v + u;
    __syncthreads();
  }
  int offset = (tid > 0) ? sums[tid - 1] : 0;
  if (tid == 0) rowptr[0] = 0;
#pragma unroll
  for (int i = 0; i < 16; i++) rowptr[base + i + 1] = loc[i] + offset;
}

__global__ void k_fill(const int* __restrict__ src, const int* __restrict__ dst,
                       const int* __restrict__ rowptr, int* __restrict__ fill,
                       int* __restrict__ eidx) {
  int e = blockIdx.x * blockDim.x + threadIdx.x;
  if (e >= NESL) return;
  int d = e < NE ? dst[e] : e - NE;
  int pos = rowptr[d] + atomicAdd(fill + d, 1);
  eidx[pos] = e;
}

// ---------------- fp32 vector GEMM (small shapes: GAT2, ARMA2) ----------------
template <int BM, int BN, int TM, int TN, typename TA, typename TC>
__global__ void gemm_nn(const TA* __restrict__ A, const float* __restrict__ B,
                        TC* __restrict__ C, int N, int K, int M) {
  constexpr int BK = 16;
  constexpr int NT = (BM / TM) * (BN / TN);  // 256
  __shared__ float As[BK][BM + 4];
  __shared__ float Bs[BK][BN + 4];
  const int tid = threadIdx.x;
  const int tx = tid % (BN / TN);
  const int ty = tid / (BN / TN);
  const int row0 = blockIdx.y * BM;
  const int col0 = blockIdx.x * BN;
  float acc[TM][TN] = {};
  for (int k0 = 0; k0 < K; k0 += BK) {
    for (int i = tid; i < BM * BK; i += NT) {
      int m = i / BK, k = i % BK;
      As[k][m] = toF(A[(size_t)(row0 + m) * K + k0 + k]);
    }
    for (int i = tid; i < BK * BN; i += NT) {
      int k = i / BN, n = i % BN;
      Bs[k][n] = B[(size_t)(k0 + k) * M + col0 + n];
    }
    __syncthreads();
#pragma unroll
    for (int k = 0; k < BK; ++k) {
      float a[TM], b[TN];
#pragma unroll
      for (int i = 0; i < TM; i++) a[i] = As[k][ty * TM + i];
#pragma unroll
      for (int j = 0; j < TN; j++) b[j] = Bs[k][tx * TN + j];
#pragma unroll
      for (int i = 0; i < TM; i++)
#pragma unroll
        for (int j = 0; j < TN; j++) acc[i][j] += a[i] * b[j];
    }
    __syncthreads();
  }
#pragma unroll
  for (int i = 0; i < TM; i++) {
    size_t r = row0 + ty * TM + i;
#pragma unroll
    for (int j = 0; j < TN; j++) stO(&C[r * M + col0 + tx * TN + j], acc[i][j]);
  }
}

// ---------------- split-bf16 prep kernels ----------------

// W [K,N] fp32 -> Wt hi/lo [N,K] bf16-bits (transposed, split)
__global__ void k_wsplit(const float* __restrict__ w, short* __restrict__ hi,
                         short* __restrict__ lo, int K, int N) {
  int i = blockIdx.x * blockDim.x + threadIdx.x;
  if (i >= N * K) return;
  int n = i / K, k = i % K;
  float v = w[(size_t)k * N + n];
  short h = bfbits(v);
  bf16 hb = *(bf16*)&h;
  short l = bfbits(v - __bfloat162float(hb));
  hi[i] = h;
  lo[i] = l;
}

// A [M,K] fp32 -> hi/lo bf16-bits (elementwise split)
__global__ void k_asplit(const float* __restrict__ a, short* __restrict__ hi,
                         short* __restrict__ lo, size_t total) {
  size_t i = (size_t)blockIdx.x * blockDim.x + threadIdx.x;
  if (i >= total) return;
  float v = a[i];
  short h = bfbits(v);
  bf16 hb = *(bf16*)&h;
  hi[i] = h;
  lo[i] = bfbits(v - __bfloat162float(hb));
}

// ---------------- MFMA GEMM: C = A @ B, A [M,K] bf16 hi(/lo), Bt [N,K] bf16 hi+lo ----
// 128x128 tile, 4 waves (2x2), 16x16x32 bf16 MFMA, split-bf16 accumulation.
__device__ __forceinline__ int swz(int row, int kbyte) {
  return ((row << 6) + kbyte) ^ ((row & 7) << 4);
}

template <bool SPLITA, bool CBF16>
__global__ __launch_bounds__(256) void gemm_mfma(const short* __restrict__ Ahi,
                                                 const short* __restrict__ Alo,
                                                 const short* __restrict__ Bthi,
                                                 const short* __restrict__ Btlo,
                                                 void* __restrict__ Cp, int M, int N, int K) {
  __shared__ short sA[2][128 * 32];
  __shared__ short sB[2][128 * 32];
  const int tid = threadIdx.x;
  const int wave = tid >> 6, lane = tid & 63;
  const int wm = wave >> 1, wn = wave & 1;
  const int row0 = blockIdx.y * 128, col0 = blockIdx.x * 128;
  const int lr = lane & 15;
  const int lkb = ((lane >> 4) << 3) * 2;  // k byte offset: 0,16,32,48
  f32x4 acc[4][4] = {};

  for (int k0 = 0; k0 < K; k0 += 32) {
#pragma unroll
    for (int i = tid; i < 512; i += 256) {
      int r = i >> 2, kk = (i & 3) << 3;
      int b = swz(r, kk * 2);
      size_t ga = (size_t)(row0 + r) * K + k0 + kk;
      *(short8v*)((char*)sA[0] + b) = *(const short8v*)(Ahi + ga);
      if (SPLITA) *(short8v*)((char*)sA[1] + b) = *(const short8v*)(Alo + ga);
      size_t gb = (size_t)(col0 + r) * K + k0 + kk;
      *(short8v*)((char*)sB[0] + b) = *(const short8v*)(Bthi + gb);
      *(short8v*)((char*)sB[1] + b) = *(const short8v*)(Btlo + gb);
    }
    __syncthreads();
    short8v af[4], al[4], bh[4], bl[4];
#pragma unroll
    for (int f = 0; f < 4; f++) {
      int r = wm * 64 + f * 16 + lr;
      int b = swz(r, lkb);
      af[f] = *(short8v*)((char*)sA[0] + b);
      if (SPLITA) al[f] = *(short8v*)((char*)sA[1] + b);
      int c = wn * 64 + f * 16 + lr;
      int b2 = swz(c, lkb);
      bh[f] = *(short8v*)((char*)sB[0] + b2);
      bl[f] = *(short8v*)((char*)sB[1] + b2);
    }
#pragma unroll
    for (int i = 0; i < 4; i++)
#pragma unroll
      for (int j = 0; j < 4; j++) {
        acc[i][j] = __builtin_amdgcn_mfma_f32_16x16x32_bf16(af[i], bh[j], acc[i][j], 0, 0, 0);
        acc[i][j] = __builtin_amdgcn_mfma_f32_16x16x32_bf16(af[i], bl[j], acc[i][j], 0, 0, 0);
        if (SPLITA)
          acc[i][j] = __builtin_amdgcn_mfma_f32_16x16x32_bf16(al[i], bh[j], acc[i][j], 0, 0, 0);
      }
    __syncthreads();
  }
#pragma unroll
  for (int i = 0; i < 4; i++)
#pragma unroll
    for (int j = 0; j < 4; j++)
#pragma unroll
      for (int r = 0; r < 4; r++) {
        int row = row0 + wm * 64 + i * 16 + ((lane >> 4) << 2) + r;
        int col = col0 + wn * 64 + j * 16 + lr;
        float v = acc[i][j][r];
        if (CBF16) {
          bf16 h = __float2bfloat16(v);
          ((short*)Cp)[(size_t)row * N + col] = *(short*)&h;
        } else {
          ((float*)Cp)[(size_t)row * N + col] = v;
        }
      }
}

// ---------------- GAT attention ----------------

__device__ __forceinline__ unsigned enc_f32(float f) {
  unsigned u = __float_as_uint(f);
  return (u & 0x80000000u) ? ~u : (u | 0x80000000u);
}
__device__ __forceinline__ float dec_f32(unsigned u) {
  return (u & 0x80000000u) ? __uint_as_float(u & 0x7fffffffu) : __uint_as_float(~u);
}

// GAT1 is rank-1 (input feature dim == 1): logits computed analytically.
__global__ void k_logits1(const float* __restrict__ x, const float* __restrict__ wl,
                          const float* __restrict__ wr, const float* __restrict__ att,
                          const int* __restrict__ src, const int* __restrict__ dst,
                          float* __restrict__ el, unsigned* __restrict__ menc) {
  int e = blockIdx.x * (blockDim.x >> 6) + (threadIdx.x >> 6);
  if (e >= NESL) return;
  int lane = threadIdx.x & 63;
  int s = e < NE ? src[e] : e - NE;
  int d = e < NE ? dst[e] : e - NE;
  float v = x[s] * wl[lane] + x[d] * wr[lane];
  v = v > 0.0f ? v : 0.2f * v;
  float acc = att[lane] * v;
#pragma unroll
  for (int off = 32; off; off >>= 1) acc += __shfl_xor(acc, off);
  if (lane == 0) {
    el[e] = acc;
    atomicMax(menc + d, enc_f32(acc));
  }
}

template <int FO, typename XT>
__global__ void k_logits(const XT* __restrict__ xl, const XT* __restrict__ xr,
                         const float* __restrict__ att, const int* __restrict__ src,
                         const int* __restrict__ dst, float* __restrict__ el,
                         unsigned* __restrict__ menc) {
  int e = blockIdx.x * (blockDim.x >> 6) + (threadIdx.x >> 6);
  if (e >= NESL) return;
  int lane = threadIdx.x & 63;
  int s = e < NE ? src[e] : e - NE;
  int d = e < NE ? dst[e] : e - NE;
  float acc = 0.0f;
  for (int f = lane; f < FO; f += 64) {
    float v = toF(xl[(size_t)s * FO + f]) + toF(xr[(size_t)d * FO + f]);
    v = v > 0.0f ? v : 0.2f * v;
    acc += att[f] * v;
  }
#pragma unroll
  for (int off = 32; off; off >>= 1) acc += __shfl_xor(acc, off);
  if (lane == 0) {
    el[e] = acc;
    atomicMax(menc + d, enc_f32(acc));
  }
}

__global__ void k_expsum(const float* __restrict__ el, const int* __restrict__ dst,
                         const unsigned* __restrict__ menc, float* __restrict__ p,
                         float* __restrict__ ssum) {
  int e = blockIdx.x * blockDim.x + threadIdx.x;
  if (e >= NESL) return;
  int d = e < NE ? dst[e] : e - NE;
  float m = dec_f32(menc[d]);
  float pe = expf(el[e] - m);
  p[e] = pe;
  atomicAdd(ssum + d, pe);
}

// GAT1 aggregation: out[n,f] = elu(wl[f]*(sum_e a_e x[src]) + b[f])
__global__ void k_agg1(const float* __restrict__ x, const float* __restrict__ p,
                       const float* __restrict__ ssum, const int* __restrict__ rowptr,
                       const int* __restrict__ eidx, const int* __restrict__ src,
                       const float* __restrict__ wl, const float* __restrict__ bias,
                       float* __restrict__ out) {
  int node = blockIdx.x * (blockDim.x >> 6) + (threadIdx.x >> 6);
  if (node >= NN) return;
  int lane = threadIdx.x & 63;
  int beg = rowptr[node], end = rowptr[node + 1];
  float acc = 0.0f;
  for (int k = beg + lane; k < end; k += 64) {
    int e = eidx[k];
    int s = e < NE ? src[e] : e - NE;
    acc += p[e] * x[s];
  }
#pragma unroll
  for (int off = 32; off; off >>= 1) acc += __shfl_xor(acc, off);
  float inv = 1.0f / (ssum[node] + 1e-16f);
  float o = acc * inv * wl[lane] + bias[lane];
  out[(size_t)node * 64 + lane] = o > 0.0f ? o : expf(o) - 1.0f;
}

// FO >= 256: one block per (node, 256-channel chunk); fused bias + elu
template <typename XT, typename OT>
__global__ void k_gat_agg_big(const XT* __restrict__ xl, const float* __restrict__ p,
                              const float* __restrict__ ssum, const int* __restrict__ rowptr,
                              const int* __restrict__ eidx, const int* __restrict__ src,
                              int FO, const float* __restrict__ bias, OT* __restrict__ out) {
  int node = blockIdx.x;
  int c = blockIdx.y * 256 + threadIdx.x;
  float inv = 1.0f / (ssum[node] + 1e-16f);
  float acc = 0.0f;
  int beg = rowptr[node], end = rowptr[node + 1];
  for (int k = beg; k < end; k++) {
    int e = eidx[k];
    int s = e < NE ? src[e] : e - NE;
    acc += p[e] * inv * toF(xl[(size_t)s * FO + c]);
  }
  acc += bias[c];
  stO(&out[(size_t)node * FO + c], acc > 0.0f ? acc : expf(acc) - 1.0f);
}

// ---------------- ARMA aggregation (fused add + relu) ----------------

__global__ void k_arma_agg_big(const float* __restrict__ t, const float* __restrict__ normv,
                               const int* __restrict__ rowptr, const int* __restrict__ eidx,
                               const int* __restrict__ src, int C,
                               const float* __restrict__ xwr, const float* __restrict__ bias,
                               float* __restrict__ out) {
  int node = blockIdx.x;
  int c = blockIdx.y * 256 + threadIdx.x;
  float acc = 0.0f;
  int beg = rowptr[node], end = rowptr[node + 1];
  for (int k = beg; k < end; k++) {
    int e = eidx[k];
    if (e >= NE) continue;  // no self loops in ARMA
    acc += normv[e] * t[(size_t)src[e] * C + c];
  }
  acc += xwr[(size_t)node * C + c] + bias[c];
  out[(size_t)node * C + c] = fmaxf(acc, 0.0f);
}

__global__ void k_arma_agg64(const float* __restrict__ t, const float* __restrict__ normv,
                             const int* __restrict__ rowptr, const int* __restrict__ eidx,
                             const int* __restrict__ src, const float* __restrict__ xwr,
                             const float* __restrict__ bias, float* __restrict__ out) {
  int node = blockIdx.x * (blockDim.x >> 6) + (threadIdx.x >> 6);
  if (node >= NN) return;
  int lane = threadIdx.x & 63;
  float acc = 0.0f;
  int beg = rowptr[node], end = rowptr[node + 1];
  for (int k = beg; k < end; k++) {
    int e = eidx[k];
    if (e >= NE) continue;
    acc += normv[e] * t[(size_t)src[e] * 64 + lane];
  }
  acc += xwr[(size_t)node * 64 + lane] + bias[lane];
  out[(size_t)node * 64 + lane] = fmaxf(acc, 0.0f);
}

// ---------------- GraphNorm ----------------

template <typename T>
__global__ void k_gn_stats(const T* __restrict__ x, const int* __restrict__ R, int C,
                           float* __restrict__ s1, float* __restrict__ s2) {
  int g = blockIdx.x;
  int c = blockIdx.y * blockDim.x + threadIdx.x;
  int beg = R[g], end = R[g + 1];
  float a = 0.0f, b = 0.0f;
  for (int n = beg; n < end; n++) {
    float v = toF(x[(size_t)n * C + c]);
    a += v;
    b += v * v;
  }
  s1[g * C + c] = a;
  s2[g * C + c] = b;
}

template <typename T>
__global__ void k_gn_apply(T* __restrict__ x, const int* __restrict__ batch,
                           const float* __restrict__ cnt, const float* __restrict__ s1,
                           const float* __restrict__ s2, const float* __restrict__ w,
                           const float* __restrict__ b, const float* __restrict__ ms, int C,
                           size_t total) {
  size_t i = (size_t)blockIdx.x * blockDim.x + threadIdx.x;
  if (i >= total) return;
  int n = (int)(i / C);
  int c = (int)(i % C);
  int g = batch[n];
  float ct = cnt[g];
  float mean = s1[g * C + c] / ct;
  float mm = mean * ms[c];
  float var = s2[g * C + c] / ct - 2.0f * mm * mean + mm * mm;
  float v = toF(x[i]);
  stO(&x[i], (v - mm) * (1.0f / sqrtf(var + 1e-5f)) * w[c] + b[c]);
}

// ---------------- pooling + final linear ----------------

__global__ void k_pool(const float* __restrict__ h, const int* __restrict__ R,
                       const float* __restrict__ cnt, const float* __restrict__ lw,
                       const float* __restrict__ lb, float* __restrict__ out) {
  int g = blockIdx.x;
  int c = threadIdx.x;  // 64 threads
  int beg = R[g], end = R[g + 1];
  float mx = -INFINITY, sm = 0.0f;
  for (int n = beg; n < end; n++) {
    float v = h[(size_t)n * 64 + c];
    mx = fmaxf(mx, v);
    sm += v;
  }
  __shared__ float feat[192];
  feat[c] = mx;
  feat[64 + c] = sm / cnt[g];
  feat[128 + c] = sm;
  __syncthreads();
  if (c < 2) {
    float acc = lb[c];
    for (int j = 0; j < 192; j++) acc += feat[j] * lw[j * 2 + c];
    out[g * 2 + c] = acc;
  }
}

// ---------------- launch ----------------

extern "C" void kernel_launch(void* const* d_in, const int* in_sizes, int n_in,
                              void* d_out, int out_size, void* d_ws, size_t ws_size,
                              hipStream_t stream) {
  const float* x = (const float*)d_in[0];
  const int* ei = (const int*)d_in[1];
  const int* batch = (const int*)d_in[2];
  const float* g1wl = (const float*)d_in[3];
  const float* g1wr = (const float*)d_in[4];
  const float* g1att = (const float*)d_in[5];
  const float* g1b = (const float*)d_in[6];
  const float* g2wl = (const float*)d_in[7];
  const float* g2wr = (const float*)d_in[8];
  const float* g2att = (const float*)d_in[9];
  const float* g2b = (const float*)d_in[10];
  const float* g3wl = (const float*)d_in[11];
  const float* g3wr = (const float*)d_in[12];
  const float* g3att = (const float*)d_in[13];
  const float* g3b = (const float*)d_in[14];
  const float* gn1w = (const float*)d_in[15];
  const float* gn1b = (const float*)d_in[16];
  const float* gn1ms = (const float*)d_in[17];
  const float* gn2w = (const float*)d_in[18];
  const float* gn2b = (const float*)d_in[19];
  const float* gn2ms = (const float*)d_in[20];
  const float* gn3w = (const float*)d_in[21];
  const float* gn3b = (const float*)d_in[22];
  const float* gn3ms = (const float*)d_in[23];
  const float* gn4w = (const float*)d_in[24];
  const float* gn4b = (const float*)d_in[25];
  const float* gn4ms = (const float*)d_in[26];
  const float* gn5w = (const float*)d_in[27];
  const float* gn5b = (const float*)d_in[28];
  const float* gn5ms = (const float*)d_in[29];
  const float* a1wi = (const float*)d_in[30];
  const float* a1wr = (const float*)d_in[31];
  const float* a1b = (const float*)d_in[32];
  const float* a2wi = (const float*)d_in[33];
  const float* a2wr = (const float*)d_in[34];
  const float* a2b = (const float*)d_in[35];
  const float* linw = (const float*)d_in[36];
  const float* linb = (const float*)d_in[37];
  const int* srcp = ei;
  const int* dstp = ei + NE;
  float* out = (float*)d_out;

  float* ws = (float*)d_ws;
  size_t o = 0;
  auto alloc = [&](size_t nfloats) { float* p = ws + o; o += nfloats; return p; };
  bf16* BIGbf0 = (bf16*)alloc((size_t)NN * 1024);  // xl3; later fp32 h4
  bf16* BIGbf1 = (bf16*)alloc((size_t)NN * 1024);  // xr3 -> h3
  float* B0 = alloc((size_t)NN * 512);             // xl2 -> A2hi/A2lo -> t1
  float* B1 = alloc((size_t)NN * 512);             // xr2 -> h2 -> xwr1
  float* h1 = alloc((size_t)NN * 64);
  float* S0 = alloc((size_t)NN * 64);  // t2
  float* S1 = alloc((size_t)NN * 64);  // xwr2
  float* S2 = alloc((size_t)NN * 64);  // h5
  float* el = alloc(NESL);
  float* pbuf = alloc(NESL);
  float* ssum = alloc(NN);
  float* dis = alloc(NN);
  float* normv = alloc(NE);
  float* cnt = alloc(NG);
  float* s1 = alloc(NG * 2048);
  float* s2 = alloc(NG * 2048);
  short* WThi = (short*)alloc(512 * 2048 / 2);  // transposed weight hi (bf16 bits)
  short* WTlo = (short*)alloc(512 * 2048 / 2);
  unsigned* menc = (unsigned*)alloc(NN);
  int* deg = (int*)alloc(NN);
  int* rowptr = (int*)alloc(NN + 1);
  int* fill = (int*)alloc(NN);
  int* eidx = (int*)alloc(NESL);
  int* R = (int*)alloc(72);
  float* h4 = (float*)BIGbf0;     // fp32 NN x 512 reuse (after GAT3 done)
  short* A2hi = (short*)B0;       // NN x 512 bf16 bits (after xl2 dead)
  short* A2lo = A2hi + (size_t)NN * 512;

  // ---- preprocessing ----
  k_zero2<<<NN / 256, 256, 0, stream>>>(deg, fill, NN);
  k_ranges<<<1, 128, 0, stream>>>(batch, R, cnt);
  k_deg<<<NE / 256, 256, 0, stream>>>(dstp, deg);
  k_scan<<<1, 1024, 0, stream>>>(deg, rowptr);
  k_fill<<<(NESL + 255) / 256, 256, 0, stream>>>(srcp, dstp, rowptr, fill, eidx);
  k_dis<<<NN / 256, 256, 0, stream>>>(deg, dis);
  k_norm<<<NE / 256, 256, 0, stream>>>(srcp, dstp, dis, normv);

  // ---- GAT1 (1 -> 64, rank-1) ----
  k_zero<<<NN / 256, 256, 0, stream>>>((float*)menc, NN);
  k_zero<<<NN / 256, 256, 0, stream>>>(ssum, NN);
  k_logits1<<<(NESL + 3) / 4, 256, 0, stream>>>(x, g1wl, g1wr, g1att, srcp, dstp, el, menc);
  k_expsum<<<(NESL + 255) / 256, 256, 0, stream>>>(el, dstp, menc, pbuf, ssum);
  k_agg1<<<NN / 4, 256, 0, stream>>>(x, pbuf, ssum, rowptr, eidx, srcp, g1wl, g1b, h1);
  k_gn_stats<float><<<dim3(NG, 1), 64, 0, stream>>>(h1, R, 64, s1, s2);
  k_gn_apply<float><<<(NN * 64 + 255) / 256, 256, 0, stream>>>(h1, batch, cnt, s1, s2, gn1w,
                                                               gn1b, gn1ms, 64, (size_t)NN * 64);

  // ---- GAT2 (64 -> 512) ----
  gemm_nn<128, 128, 8, 8, float, float><<<dim3(4, 128), 256, 0, stream>>>(h1, g2wl, B0, NN, 64, 512);
  gemm_nn<128, 128, 8, 8, float, float><<<dim3(4, 128), 256, 0, stream>>>(h1, g2wr, B1, NN, 64, 512);
  k_zero<<<NN / 256, 256, 0, stream>>>((float*)menc, NN);
  k_zero<<<NN / 256, 256, 0, stream>>>(ssum, NN);
  k_logits<512, float><<<(NESL + 3) / 4, 256, 0, stream>>>(B0, B1, g2att, srcp, dstp, el, menc);
  k_expsum<<<(NESL + 255) / 256, 256, 0, stream>>>(el, dstp, menc, pbuf, ssum);
  k_gat_agg_big<float, float><<<dim3(NN, 2), 256, 0, stream>>>(B0, pbuf, ssum, rowptr, eidx,
                                                               srcp, 512, g2b, B1);
  k_gn_stats<float><<<dim3(NG, 2), 256, 0, stream>>>(B1, R, 512, s1, s2);
  k_gn_apply<float><<<(NN * 512 + 255) / 256, 256, 0, stream>>>(B1, batch, cnt, s1, s2, gn2w,
                                                                gn2b, gn2ms, 512, (size_t)NN * 512);

  // ---- GAT3 (512 -> 2048) via split-bf16 MFMA ----
  k_asplit<<<(NN * 512 + 255) / 256, 256, 0, stream>>>(B1, A2hi, A2lo, (size_t)NN * 512);
  k_wsplit<<<(512 * 2048 + 255) / 256, 256, 0, stream>>>(g3wl, WThi, WTlo, 512, 2048);
  gemm_mfma<true, true><<<dim3(16, 128), 256, 0, stream>>>(A2hi, A2lo, WThi, WTlo,
                                                           (void*)BIGbf0, NN, 2048, 512);
  k_wsplit<<<(512 * 2048 + 255) / 256, 256, 0, stream>>>(g3wr, WThi, WTlo, 512, 2048);
  gemm_mfma<true, true><<<dim3(16, 128), 256, 0, stream>>>(A2hi, A2lo, WThi, WTlo,
                                                           (void*)BIGbf1, NN, 2048, 512);
  k_zero<<<NN / 256, 256, 0, stream>>>((float*)menc, NN);
  k_zero<<<NN / 256, 256, 0, stream>>>(ssum, NN);
  k_logits<2048, bf16><<<(NESL + 3) / 4, 256, 0, stream>>>(BIGbf0, BIGbf1, g3att, srcp, dstp, el, menc);
  k_expsum<<<(NESL + 255) / 256, 256, 0, stream>>>(el, dstp, menc, pbuf, ssum);
  k_gat_agg_big<bf16, bf16><<<dim3(NN, 8), 256, 0, stream>>>(BIGbf0, pbuf, ssum, rowptr, eidx,
                                                             srcp, 2048, g3b, BIGbf1);
  k_gn_stats<bf16><<<dim3(NG, 8), 256, 0, stream>>>(BIGbf1, R, 2048, s1, s2);
  k_gn_apply<bf16><<<(size_t)NN * 2048 / 256, 256, 0, stream>>>(BIGbf1, batch, cnt, s1, s2, gn3w,
                                                                gn3b, gn3ms, 2048, (size_t)NN * 2048);

  // ---- ARMA1 (2048 -> 512) via MFMA (A already bf16; weights split) ----
  k_wsplit<<<(512 * 2048 + 255) / 256, 256, 0, stream>>>(a1wi, WThi, WTlo, 2048, 512);
  gemm_mfma<false, false><<<dim3(4, 128), 256, 0, stream>>>((const short*)BIGbf1, nullptr, WThi,
                                                            WTlo, (void*)B0, NN, 512, 2048);
  k_wsplit<<<(512 * 2048 + 255) / 256, 256, 0, stream>>>(a1wr, WThi, WTlo, 2048, 512);
  gemm_mfma<false, false><<<dim3(4, 128), 256, 0, stream>>>((const short*)BIGbf1, nullptr, WThi,
                                                            WTlo, (void*)B1, NN, 512, 2048);
  k_arma_agg_big<<<dim3(NN, 2), 256, 0, stream>>>(B0, normv, rowptr, eidx, srcp, 512, B1, a1b, h4);
  k_gn_stats<float><<<dim3(NG, 2), 256, 0, stream>>>(h4, R, 512, s1, s2);
  k_gn_apply<float><<<(NN * 512 + 255) / 256, 256, 0, stream>>>(h4, batch, cnt, s1, s2, gn4w,
                                                                gn4b, gn4ms, 512, (size_t)NN * 512);

  // ---- ARMA2 (512 -> 64) ----
  gemm_nn<64, 64, 4, 4, float, float><<<dim3(1, 256), 256, 0, stream>>>(h4, a2wi, S0, NN, 512, 64);
  gemm_nn<64, 64, 4, 4, float, float><<<dim3(1, 256), 256, 0, stream>>>(h4, a2wr, S1, NN, 512, 64);
  k_arma_agg64<<<NN / 4, 256, 0, stream>>>(S0, normv, rowptr, eidx, srcp, S1, a2b, S2);
  k_gn_stats<float><<<dim3(NG, 1), 64, 0, stream>>>(S2, R, 64, s1, s2);
  k_gn_apply<float><<<(NN * 64 + 255) / 256, 256, 0, stream>>>(S2, batch, cnt, s1, s2, gn5w,
                                                               gn5b, gn5ms, 64, (size_t)NN * 64);

  // ---- pooling + linear ----
  k_pool<<<NG, 64, 0, stream>>>(S2, R, cnt, linw, linb, out);
}

// Round 4
// 1510.386 us; speedup vs baseline: 5.0558x; 1.3194x over previous
//
#include <hip/hip_runtime.h>
#include <hip/hip_bf16.h>

#define NN 16384
#define NE 65536
#define NESL (NE + NN)
#define NG 64

typedef __hip_bfloat16 bf16;
typedef __attribute__((ext_vector_type(8))) short short8v;
typedef __attribute__((ext_vector_type(4))) float f32x4;

__device__ __forceinline__ float toF(float v) { return v; }
__device__ __forceinline__ float toF(bf16 v) { return __bfloat162float(v); }
__device__ __forceinline__ void stO(float* p, float v) { *p = v; }
__device__ __forceinline__ void stO(bf16* p, float v) { *p = __float2bfloat16(v); }
__device__ __forceinline__ short bfbits(float v) {
  bf16 h = __float2bfloat16(v);
  return *(short*)&h;
}
__device__ __forceinline__ float bfs2f(short s) {
  return __uint_as_float(((unsigned)(unsigned short)s) << 16);
}

// ---------------- utility ----------------
__global__ void k_zero(float* a, int n) {
  int i = blockIdx.x * blockDim.x + threadIdx.x;
  if (i < n) a[i] = 0.0f;
}
__global__ void k_zero2(int* a, int* b, int n) {
  int i = blockIdx.x * blockDim.x + threadIdx.x;
  if (i < n) { a[i] = 0; b[i] = 0; }
}

// ---------------- graph preprocessing ----------------

__global__ void k_ranges(const int* __restrict__ batch, int* __restrict__ R,
                         float* __restrict__ cnt) {
  int g = threadIdx.x;
  if (g <= NG) {
    int lo = 0, hi = NN;
    while (lo < hi) { int mid = (lo + hi) >> 1; if (batch[mid] < g) lo = mid + 1; else hi = mid; }
    R[g] = lo;
  }
  __syncthreads();
  if (g < NG) cnt[g] = fmaxf((float)(R[g + 1] - R[g]), 1.0f);
}

__global__ void k_deg(const int* __restrict__ dst, int* __restrict__ deg) {
  int e = blockIdx.x * blockDim.x + threadIdx.x;
  if (e < NE) atomicAdd(deg + dst[e], 1);
}

__global__ void k_dis(const int* __restrict__ deg, float* __restrict__ dis) {
  int n = blockIdx.x * blockDim.x + threadIdx.x;
  if (n < NN) { int d = deg[n]; dis[n] = d > 0 ? 1.0f / sqrtf((float)d) : 0.0f; }
}

__global__ void k_norm(const int* __restrict__ src, const int* __restrict__ dst,
                       const float* __restrict__ dis, float* __restrict__ normv) {
  int e = blockIdx.x * blockDim.x + threadIdx.x;
  if (e < NE) normv[e] = dis[src[e]] * dis[dst[e]];
}

__global__ void k_scan(const int* __restrict__ deg, int* __restrict__ rowptr) {
  __shared__ int sums[1024];
  int tid = threadIdx.x;
  int base = tid * 16;
  int loc[16];
  int run = 0;
#pragma unroll
  for (int i = 0; i < 16; i++) { run += deg[base + i] + 1; loc[i] = run; }
  sums[tid] = run;
  __syncthreads();
  for (int off = 1; off < 1024; off <<= 1) {
    int v = sums[tid];
    int u = (tid >= off) ? sums[tid - off] : 0;
    __syncthreads();
    sums[tid] = v + u;
    __syncthreads();
  }
  int offset = (tid > 0) ? sums[tid - 1] : 0;
  if (tid == 0) rowptr[0] = 0;
#pragma unroll
  for (int i = 0; i < 16; i++) rowptr[base + i + 1] = loc[i] + offset;
}

__global__ void k_fill(const int* __restrict__ src, const int* __restrict__ dst,
                       const int* __restrict__ rowptr, int* __restrict__ fill,
                       int* __restrict__ eidx) {
  int e = blockIdx.x * blockDim.x + threadIdx.x;
  if (e >= NESL) return;
  int d = e < NE ? dst[e] : e - NE;
  int pos = rowptr[d] + atomicAdd(fill + d, 1);
  eidx[pos] = e;
}

// ---------------- split-bf16 weight prep ----------------

// W [K,N] fp32 -> Bt hi/lo [N,K] bf16-bits (transposed, split)
__global__ void k_wsplit(const float* __restrict__ w, short* __restrict__ hi,
                         short* __restrict__ lo, int K, int N) {
  int i = blockIdx.x * blockDim.x + threadIdx.x;
  if (i >= N * K) return;
  int n = i / K, k = i % K;
  float v = w[(size_t)k * N + n];
  short h = bfbits(v);
  hi[i] = h;
  lo[i] = bfbits(v - bfs2f(h));
}

// ---------------- MFMA GEMM ----------------
// C[M,N] = A[M,K] @ Bt[N,K]^T.  128x128 tile, 4 waves, 16x16x32 bf16 MFMA.
// AMODE 0: A fp32, split hi+lo (3 MFMA)   [fp32-grade]
// AMODE 1: A bf16 direct (2 MFMA)
// AMODE 2: A fp32, hi only (2 MFMA)       [bf16-grade A]
// ACT: 0 none, 1 elu, 2 relu.  CBF16: store bf16 vs f32.
__device__ __forceinline__ int swz(int row, int kbyte) {
  return ((row << 6) + kbyte) ^ ((row & 7) << 4);
}

__device__ __forceinline__ void splitw2(const float* ap, char* hidst, char* lodst) {
  f32x4 va = *(const f32x4*)ap;
  f32x4 vb = *(const f32x4*)(ap + 4);
  float f[8] = {va[0], va[1], va[2], va[3], vb[0], vb[1], vb[2], vb[3]};
  short8v h, l;
#pragma unroll
  for (int j = 0; j < 8; j++) {
    short hb = bfbits(f[j]);
    h[j] = hb;
    l[j] = bfbits(f[j] - bfs2f(hb));
  }
  *(short8v*)hidst = h;
  *(short8v*)lodst = l;
}
__device__ __forceinline__ void splitw1(const float* ap, char* hidst) {
  f32x4 va = *(const f32x4*)ap;
  f32x4 vb = *(const f32x4*)(ap + 4);
  float f[8] = {va[0], va[1], va[2], va[3], vb[0], vb[1], vb[2], vb[3]};
  short8v h;
#pragma unroll
  for (int j = 0; j < 8; j++) h[j] = bfbits(f[j]);
  *(short8v*)hidst = h;
}

template <int AMODE, int CBF16, int ACT>
__global__ __launch_bounds__(256) void gemm_mfma(const void* __restrict__ Ap,
                                                 const short* __restrict__ Bthi,
                                                 const short* __restrict__ Btlo,
                                                 void* __restrict__ Cp,
                                                 const float* __restrict__ bias,
                                                 int M, int N, int K) {
  __shared__ __align__(16) short sAhi[128 * 32];
  __shared__ __align__(16) short sAlo[(AMODE == 0) ? 128 * 32 : 16];
  __shared__ __align__(16) short sBhi[128 * 32];
  __shared__ __align__(16) short sBlo[128 * 32];
  const int tid = threadIdx.x;
  const int wave = tid >> 6, lane = tid & 63;
  const int wm = wave >> 1, wn = wave & 1;
  const int row0 = blockIdx.y * 128, col0 = blockIdx.x * 128;
  const int lr = lane & 15;
  const int lkb = (lane >> 4) * 16;  // k byte offset within 64B row
  f32x4 acc[4][4] = {};

  for (int k0 = 0; k0 < K; k0 += 32) {
#pragma unroll
    for (int i = tid; i < 512; i += 256) {
      int r = i >> 2, kk = (i & 3) << 3;
      int b = swz(r, kk * 2);
      size_t gb = (size_t)(col0 + r) * K + k0 + kk;
      *(short8v*)((char*)sBhi + b) = *(const short8v*)(Bthi + gb);
      *(short8v*)((char*)sBlo + b) = *(const short8v*)(Btlo + gb);
    }
    if constexpr (AMODE == 1) {
      const short* Ab = (const short*)Ap;
#pragma unroll
      for (int i = tid; i < 512; i += 256) {
        int r = i >> 2, kk = (i & 3) << 3;
        *(short8v*)((char*)sAhi + swz(r, kk * 2)) =
            *(const short8v*)(Ab + (size_t)(row0 + r) * K + k0 + kk);
      }
    } else {
      int r = tid >> 1, kb = (tid & 1) * 16;
      const float* ap = (const float*)Ap + (size_t)(row0 + r) * K + k0 + kb;
      if constexpr (AMODE == 0) {
        splitw2(ap, (char*)sAhi + swz(r, kb * 2), (char*)sAlo + swz(r, kb * 2));
        splitw2(ap + 8, (char*)sAhi + swz(r, kb * 2 + 16), (char*)sAlo + swz(r, kb * 2 + 16));
      } else {
        splitw1(ap, (char*)sAhi + swz(r, kb * 2));
        splitw1(ap + 8, (char*)sAhi + swz(r, kb * 2 + 16));
      }
    }
    __syncthreads();
    short8v af[4], al[4], bh[4], bl[4];
#pragma unroll
    for (int f = 0; f < 4; f++) {
      int b = swz(wm * 64 + f * 16 + lr, lkb);
      af[f] = *(short8v*)((char*)sAhi + b);
      if constexpr (AMODE == 0) al[f] = *(short8v*)((char*)sAlo + b);
      int b2 = swz(wn * 64 + f * 16 + lr, lkb);
      bh[f] = *(short8v*)((char*)sBhi + b2);
      bl[f] = *(short8v*)((char*)sBlo + b2);
    }
#pragma unroll
    for (int i = 0; i < 4; i++)
#pragma unroll
      for (int j = 0; j < 4; j++) {
        acc[i][j] = __builtin_amdgcn_mfma_f32_16x16x32_bf16(af[i], bh[j], acc[i][j], 0, 0, 0);
        acc[i][j] = __builtin_amdgcn_mfma_f32_16x16x32_bf16(af[i], bl[j], acc[i][j], 0, 0, 0);
        if constexpr (AMODE == 0)
          acc[i][j] = __builtin_amdgcn_mfma_f32_16x16x32_bf16(al[i], bh[j], acc[i][j], 0, 0, 0);
      }
    __syncthreads();
  }
#pragma unroll
  for (int i = 0; i < 4; i++)
#pragma unroll
    for (int j = 0; j < 4; j++)
#pragma unroll
      for (int r = 0; r < 4; r++) {
        int row = row0 + wm * 64 + i * 16 + ((lane >> 4) << 2) + r;
        int col = col0 + wn * 64 + j * 16 + lr;
        float v = acc[i][j][r];
        if (bias) v += bias[col];
        if constexpr (ACT == 1) v = v > 0.0f ? v : expf(v) - 1.0f;
        if constexpr (ACT == 2) v = fmaxf(v, 0.0f);
        if constexpr (CBF16) {
          bf16 h = __float2bfloat16(v);
          ((short*)Cp)[(size_t)row * N + col] = *(short*)&h;
        } else {
          ((float*)Cp)[(size_t)row * N + col] = v;
        }
      }
}

// ---------------- GAT attention ----------------

__device__ __forceinline__ unsigned enc_f32(float f) {
  unsigned u = __float_as_uint(f);
  return (u & 0x80000000u) ? ~u : (u | 0x80000000u);
}
__device__ __forceinline__ float dec_f32(unsigned u) {
  return (u & 0x80000000u) ? __uint_as_float(u & 0x7fffffffu) : __uint_as_float(~u);
}

__global__ void k_logits1(const float* __restrict__ x, const float* __restrict__ wl,
                          const float* __restrict__ wr, const float* __restrict__ att,
                          const int* __restrict__ src, const int* __restrict__ dst,
                          float* __restrict__ el, unsigned* __restrict__ menc) {
  int e = blockIdx.x * (blockDim.x >> 6) + (threadIdx.x >> 6);
  if (e >= NESL) return;
  int lane = threadIdx.x & 63;
  int s = e < NE ? src[e] : e - NE;
  int d = e < NE ? dst[e] : e - NE;
  float v = x[s] * wl[lane] + x[d] * wr[lane];
  v = v > 0.0f ? v : 0.2f * v;
  float acc = att[lane] * v;
#pragma unroll
  for (int off = 32; off; off >>= 1) acc += __shfl_xor(acc, off);
  if (lane == 0) {
    el[e] = acc;
    atomicMax(menc + d, enc_f32(acc));
  }
}

// combined X = [xl | xr], row stride STR, xl at col 0, xr at col FO
template <int FO, int STR, typename XT>
__global__ void k_logits(const XT* __restrict__ X, const float* __restrict__ att,
                         const int* __restrict__ src, const int* __restrict__ dst,
                         float* __restrict__ el, unsigned* __restrict__ menc) {
  int e = blockIdx.x * (blockDim.x >> 6) + (threadIdx.x >> 6);
  if (e >= NESL) return;
  int lane = threadIdx.x & 63;
  int s = e < NE ? src[e] : e - NE;
  int d = e < NE ? dst[e] : e - NE;
  float acc = 0.0f;
  if constexpr (sizeof(XT) == 2) {
    const short* xl = (const short*)X + (size_t)s * STR;
    const short* xr = (const short*)X + (size_t)d * STR + FO;
#pragma unroll
    for (int j = 0; j < FO / 512; j++) {
      int f0 = j * 512 + lane * 8;
      short8v a = *(const short8v*)(xl + f0);
      short8v b = *(const short8v*)(xr + f0);
#pragma unroll
      for (int t = 0; t < 8; t++) {
        float v = bfs2f(a[t]) + bfs2f(b[t]);
        v = v > 0.0f ? v : 0.2f * v;
        acc += att[f0 + t] * v;
      }
    }
  } else {
    const float* xl = (const float*)X + (size_t)s * STR;
    const float* xr = (const float*)X + (size_t)d * STR + FO;
#pragma unroll
    for (int j = 0; j < FO / 256; j++) {
      int f0 = j * 256 + lane * 4;
      f32x4 a = *(const f32x4*)(xl + f0);
      f32x4 b = *(const f32x4*)(xr + f0);
#pragma unroll
      for (int t = 0; t < 4; t++) {
        float v = a[t] + b[t];
        v = v > 0.0f ? v : 0.2f * v;
        acc += att[f0 + t] * v;
      }
    }
  }
#pragma unroll
  for (int off = 32; off; off >>= 1) acc += __shfl_xor(acc, off);
  if (lane == 0) {
    el[e] = acc;
    atomicMax(menc + d, enc_f32(acc));
  }
}

__global__ void k_expsum(const float* __restrict__ el, const int* __restrict__ dst,
                         const unsigned* __restrict__ menc, float* __restrict__ p,
                         float* __restrict__ ssum) {
  int e = blockIdx.x * blockDim.x + threadIdx.x;
  if (e >= NESL) return;
  int d = e < NE ? dst[e] : e - NE;
  float m = dec_f32(menc[d]);
  float pe = expf(el[e] - m);
  p[e] = pe;
  atomicAdd(ssum + d, pe);
}

// GAT1 (rank-1): out[n,f] = elu(wl[f]*(sum_e a_e x[src]) + b[f])
__global__ void k_agg1(const float* __restrict__ x, const float* __restrict__ p,
                       const float* __restrict__ ssum, const int* __restrict__ rowptr,
                       const int* __restrict__ eidx, const int* __restrict__ src,
                       const float* __restrict__ wl, const float* __restrict__ bias,
                       float* __restrict__ out) {
  int node = blockIdx.x * (blockDim.x >> 6) + (threadIdx.x >> 6);
  if (node >= NN) return;
  int lane = threadIdx.x & 63;
  int beg = rowptr[node], end = rowptr[node + 1];
  float acc = 0.0f;
  for (int k = beg + lane; k < end; k += 64) {
    int e = eidx[k];
    int s = e < NE ? src[e] : e - NE;
    acc += p[e] * x[s];
  }
#pragma unroll
  for (int off = 32; off; off >>= 1) acc += __shfl_xor(acc, off);
  float inv = 1.0f / (ssum[node] + 1e-16f);
  float o = acc * inv * wl[lane] + bias[lane];
  out[(size_t)node * 64 + lane] = o > 0.0f ? o : expf(o) - 1.0f;
}

// ---------------- vectorized gather-aggregation ----------------
// 512-wide. MODE 0: GAT softmax-weighted (self-loops incl., raw out)
//           MODE 1: ARMA norm-weighted (+ xwr + bias, relu)
template <int MODE, int SSTR, int OSTR>
__global__ void k_agg512(const float* __restrict__ Xsrc, const float* __restrict__ wgt,
                         const float* __restrict__ ssum, const int* __restrict__ rowptr,
                         const int* __restrict__ eidx, const int* __restrict__ src,
                         const float* __restrict__ xwrb, const float* __restrict__ bias,
                         float* __restrict__ out) {
  int wave = threadIdx.x >> 6;
  int node = blockIdx.x * 2 + (wave >> 1);
  int lane = threadIdx.x & 63;
  int c0 = (wave & 1) * 256 + lane * 4;
  f32x4 acc = {};
  int beg = rowptr[node], end = rowptr[node + 1];
  float inv = (MODE == 0) ? 1.0f / (ssum[node] + 1e-16f) : 1.0f;
  for (int k = beg; k < end; k++) {
    int e = eidx[k];
    if (MODE == 1 && e >= NE) continue;
    int s = e < NE ? src[e] : e - NE;
    float w = (MODE == 0) ? wgt[e] * inv : wgt[e];
    f32x4 v = *(const f32x4*)(Xsrc + (size_t)s * SSTR + c0);
#pragma unroll
    for (int t = 0; t < 4; t++) acc[t] += w * v[t];
  }
  if constexpr (MODE == 1) {
    f32x4 xv = *(const f32x4*)(xwrb + (size_t)node * SSTR + 512 + c0);
#pragma unroll
    for (int t = 0; t < 4; t++) acc[t] = fmaxf(acc[t] + xv[t] + bias[c0 + t], 0.0f);
  }
  *(f32x4*)(out + (size_t)node * OSTR + c0) = acc;
}

// 64-wide, 4-edge ILP. MODE 0: GAT raw; MODE 1: ARMA (+xwr@XOFF + bias, relu)
template <int MODE, int SSTR, int XOFF>
__global__ void k_agg64(const float* __restrict__ Xsrc, const float* __restrict__ wgt,
                        const float* __restrict__ ssum, const int* __restrict__ rowptr,
                        const int* __restrict__ eidx, const int* __restrict__ src,
                        const float* __restrict__ xwrb, const float* __restrict__ bias,
                        float* __restrict__ out) {
  int node = blockIdx.x * (blockDim.x >> 6) + (threadIdx.x >> 6);
  if (node >= NN) return;
  int lane = threadIdx.x & 63;
  int cg = lane & 15, eg = lane >> 4;
  int c0 = cg * 4;
  f32x4 acc = {};
  int beg = rowptr[node], end = rowptr[node + 1];
  float inv = (MODE == 0) ? 1.0f / (ssum[node] + 1e-16f) : 1.0f;
  for (int k = beg + eg; k < end; k += 4) {
    int e = eidx[k];
    if (MODE == 1 && e >= NE) continue;
    int s = e < NE ? src[e] : e - NE;
    float w = (MODE == 0) ? wgt[e] * inv : wgt[e];
    f32x4 v = *(const f32x4*)(Xsrc + (size_t)s * SSTR + c0);
#pragma unroll
    for (int t = 0; t < 4; t++) acc[t] += w * v[t];
  }
#pragma unroll
  for (int t = 0; t < 4; t++) {
    acc[t] += __shfl_xor(acc[t], 16);
    acc[t] += __shfl_xor(acc[t], 32);
  }
  if (eg == 0) {
    if constexpr (MODE == 1) {
      f32x4 xv = *(const f32x4*)(xwrb + (size_t)node * SSTR + XOFF + c0);
#pragma unroll
      for (int t = 0; t < 4; t++) acc[t] = fmaxf(acc[t] + xv[t] + bias[c0 + t], 0.0f);
    }
    *(f32x4*)(out + (size_t)node * 64 + c0) = acc;
  }
}

// ---------------- GraphNorm ----------------

template <typename T>
__global__ void k_gn_stats(const T* __restrict__ x, const int* __restrict__ R, int C,
                           float* __restrict__ s1, float* __restrict__ s2) {
  int g = blockIdx.x;
  int c = blockIdx.y * blockDim.x + threadIdx.x;
  int beg = R[g], end = R[g + 1];
  float a = 0.0f, b = 0.0f;
  for (int n = beg; n < end; n++) {
    float v = toF(x[(size_t)n * C + c]);
    a += v;
    b += v * v;
  }
  s1[g * C + c] = a;
  s2[g * C + c] = b;
}

template <typename T>
__global__ void k_gn_apply(T* __restrict__ x, const int* __restrict__ batch,
                           const float* __restrict__ cnt, const float* __restrict__ s1,
                           const float* __restrict__ s2, const float* __restrict__ w,
                           const float* __restrict__ b, const float* __restrict__ ms, int C,
                           size_t total) {
  size_t i = (size_t)blockIdx.x * blockDim.x + threadIdx.x;
  if (i >= total) return;
  int n = (int)(i / C);
  int c = (int)(i % C);
  int g = batch[n];
  float ct = cnt[g];
  float mean = s1[g * C + c] / ct;
  float mm = mean * ms[c];
  float var = s2[g * C + c] / ct - 2.0f * mm * mean + mm * mm;
  float v = toF(x[i]);
  stO(&x[i], (v - mm) * (1.0f / sqrtf(var + 1e-5f)) * w[c] + b[c]);
}

// ---------------- pooling + final linear ----------------

__global__ void k_pool(const float* __restrict__ h, const int* __restrict__ R,
                       const float* __restrict__ cnt, const float* __restrict__ lw,
                       const float* __restrict__ lb, float* __restrict__ out) {
  int g = blockIdx.x;
  int c = threadIdx.x;  // 64
  int beg = R[g], end = R[g + 1];
  float mx = -INFINITY, sm = 0.0f;
  for (int n = beg; n < end; n++) {
    float v = h[(size_t)n * 64 + c];
    mx = fmaxf(mx, v);
    sm += v;
  }
  __shared__ float feat[192];
  feat[c] = mx;
  feat[64 + c] = sm / cnt[g];
  feat[128 + c] = sm;
  __syncthreads();
  if (c < 2) {
    float acc = lb[c];
    for (int j = 0; j < 192; j++) acc += feat[j] * lw[j * 2 + c];
    out[g * 2 + c] = acc;
  }
}

// ---------------- launch ----------------

extern "C" void kernel_launch(void* const* d_in, const int* in_sizes, int n_in,
                              void* d_out, int out_size, void* d_ws, size_t ws_size,
                              hipStream_t stream) {
  const float* x = (const float*)d_in[0];
  const int* ei = (const int*)d_in[1];
  const int* batch = (const int*)d_in[2];
  const float* g1wl = (const float*)d_in[3];
  const float* g1wr = (const float*)d_in[4];
  const float* g1att = (const float*)d_in[5];
  const float* g1b = (const float*)d_in[6];
  const float* g2wl = (const float*)d_in[7];
  const float* g2wr = (const float*)d_in[8];
  const float* g2att = (const float*)d_in[9];
  const float* g2b = (const float*)d_in[10];
  const float* g3wl = (const float*)d_in[11];
  const float* g3wr = (const float*)d_in[12];
  const float* g3att = (const float*)d_in[13];
  const float* g3b = (const float*)d_in[14];
  const float* gn1w = (const float*)d_in[15];
  const float* gn1b = (const float*)d_in[16];
  const float* gn1ms = (const float*)d_in[17];
  const float* gn2w = (const float*)d_in[18];
  const float* gn2b = (const float*)d_in[19];
  const float* gn2ms = (const float*)d_in[20];
  const float* gn3w = (const float*)d_in[21];
  const float* gn3b = (const float*)d_in[22];
  const float* gn3ms = (const float*)d_in[23];
  const float* gn4w = (const float*)d_in[24];
  const float* gn4b = (const float*)d_in[25];
  const float* gn4ms = (const float*)d_in[26];
  const float* gn5w = (const float*)d_in[27];
  const float* gn5b = (const float*)d_in[28];
  const float* gn5ms = (const float*)d_in[29];
  const float* a1wi = (const float*)d_in[30];
  const float* a1wr = (const float*)d_in[31];
  const float* a1b = (const float*)d_in[32];
  const float* a2wi = (const float*)d_in[33];
  const float* a2wr = (const float*)d_in[34];
  const float* a2b = (const float*)d_in[35];
  const float* linw = (const float*)d_in[36];
  const float* linb = (const float*)d_in[37];
  const int* srcp = ei;
  const int* dstp = ei + NE;
  float* out = (float*)d_out;

  float* ws = (float*)d_ws;
  size_t o = 0;
  auto alloc = [&](size_t nfloats) { float* p = ws + o; o += nfloats; return p; };
  // BIG region: holds [xl3|xr3] combined [NN][4096] bf16 (128MB), later h3 [NN][2048] bf16
  // in first half and h4 [NN][512] f32 in second half.
  float* BIG0f = alloc((size_t)NN * 1024);  // 64 MB
  float* BIG1f = alloc((size_t)NN * 1024);  // 64 MB
  // B region: [xl2|xr2] combined [NN][1024] f32 spanning B0+B1; later h2 (B0), agg2 (B1),
  // then [t1|xwr1] combined [NN][1024] f32.
  float* B0 = alloc((size_t)NN * 512);  // 32 MB
  float* B1 = alloc((size_t)NN * 512);  // 32 MB
  float* h1 = alloc((size_t)NN * 64);
  float* aggS = alloc((size_t)NN * 64);
  float* S0 = alloc((size_t)NN * 64);  // [t2|xwr2] combined [NN][128] spans S0+S1
  float* S1 = alloc((size_t)NN * 64);
  float* S2 = alloc((size_t)NN * 64);  // h5
  float* el = alloc(NESL);
  float* pbuf = alloc(NESL);
  float* ssum = alloc(NN);
  float* dis = alloc(NN);
  float* normv = alloc(NE);
  float* cnt = alloc(NG);
  float* s1 = alloc(NG * 2048);
  float* s2 = alloc(NG * 2048);
  short* WThi = (short*)alloc((size_t)4096 * 512 / 2);  // 4 MB (max combined Bt)
  short* WTlo = (short*)alloc((size_t)4096 * 512 / 2);
  unsigned* menc = (unsigned*)alloc(NN);
  int* deg = (int*)alloc(NN);
  int* rowptr = (int*)alloc(NN + 1);
  int* fill = (int*)alloc(NN);
  int* eidx = (int*)alloc(NESL);
  int* R = (int*)alloc(72);

  bf16* XLR3 = (bf16*)BIG0f;   // [NN][4096] bf16 (spans BIG0f+BIG1f)
  bf16* h3 = (bf16*)BIG0f;     // [NN][2048] bf16 (after XLR3 dead)
  float* h4 = BIG1f;           // [NN][512] f32 (after XLR3 dead)
  float* XLR2 = B0;            // [NN][1024] f32 (spans B0+B1)
  float* h2 = B0;              // [NN][512] f32
  float* agg2 = B1;            // [NN][512] f32
  float* TXW1 = B0;            // [t1|xwr1] [NN][1024] f32
  float* TXW2 = S0;            // [t2|xwr2] [NN][128] f32

  // ---- preprocessing ----
  k_zero2<<<NN / 256, 256, 0, stream>>>(deg, fill, NN);
  k_ranges<<<1, 128, 0, stream>>>(batch, R, cnt);
  k_deg<<<NE / 256, 256, 0, stream>>>(dstp, deg);
  k_scan<<<1, 1024, 0, stream>>>(deg, rowptr);
  k_fill<<<(NESL + 255) / 256, 256, 0, stream>>>(srcp, dstp, rowptr, fill, eidx);
  k_dis<<<NN / 256, 256, 0, stream>>>(deg, dis);
  k_norm<<<NE / 256, 256, 0, stream>>>(srcp, dstp, dis, normv);

  // ---- GAT1 (1 -> 64, rank-1, all fp32) ----
  k_zero<<<NN / 256, 256, 0, stream>>>((float*)menc, NN);
  k_zero<<<NN / 256, 256, 0, stream>>>(ssum, NN);
  k_logits1<<<(NESL + 3) / 4, 256, 0, stream>>>(x, g1wl, g1wr, g1att, srcp, dstp, el, menc);
  k_expsum<<<(NESL + 255) / 256, 256, 0, stream>>>(el, dstp, menc, pbuf, ssum);
  k_agg1<<<NN / 4, 256, 0, stream>>>(x, pbuf, ssum, rowptr, eidx, srcp, g1wl, g1b, h1);
  k_gn_stats<float><<<dim3(NG, 1), 64, 0, stream>>>(h1, R, 64, s1, s2);
  k_gn_apply<float><<<(NN * 64 + 255) / 256, 256, 0, stream>>>(h1, batch, cnt, s1, s2, gn1w,
                                                               gn1b, gn1ms, 64, (size_t)NN * 64);

  // ---- GAT2 (64 -> 512): combined [xl2|xr2] GEMM, agg in 64-space, project ----
  k_wsplit<<<(512 * 64 + 255) / 256, 256, 0, stream>>>(g2wl, WThi, WTlo, 64, 512);
  k_wsplit<<<(512 * 64 + 255) / 256, 256, 0, stream>>>(g2wr, WThi + 512 * 64, WTlo + 512 * 64,
                                                       64, 512);
  gemm_mfma<0, 0, 0><<<dim3(8, 128), 256, 0, stream>>>(h1, WThi, WTlo, XLR2, nullptr, NN, 1024, 64);
  k_zero<<<NN / 256, 256, 0, stream>>>((float*)menc, NN);
  k_zero<<<NN / 256, 256, 0, stream>>>(ssum, NN);
  k_logits<512, 1024, float><<<(NESL + 3) / 4, 256, 0, stream>>>(XLR2, g2att, srcp, dstp, el, menc);
  k_expsum<<<(NESL + 255) / 256, 256, 0, stream>>>(el, dstp, menc, pbuf, ssum);
  k_agg64<0, 64, 0><<<NN / 4, 256, 0, stream>>>(h1, pbuf, ssum, rowptr, eidx, srcp, nullptr,
                                                nullptr, aggS);
  // h2 = elu(aggS @ Wl2 + b2)  (WT first half still holds Wl2^T)
  gemm_mfma<0, 0, 1><<<dim3(4, 128), 256, 0, stream>>>(aggS, WThi, WTlo, h2, g2b, NN, 512, 64);
  k_gn_stats<float><<<dim3(NG, 2), 256, 0, stream>>>(h2, R, 512, s1, s2);
  k_gn_apply<float><<<(NN * 512 + 255) / 256, 256, 0, stream>>>(h2, batch, cnt, s1, s2, gn2w,
                                                                gn2b, gn2ms, 512, (size_t)NN * 512);

  // ---- GAT3 (512 -> 2048): combined [xl3|xr3] bf16, agg in 512-space, split-project ----
  k_wsplit<<<(2048 * 512 + 255) / 256, 256, 0, stream>>>(g3wl, WThi, WTlo, 512, 2048);
  k_wsplit<<<(2048 * 512 + 255) / 256, 256, 0, stream>>>(g3wr, WThi + 2048 * 512,
                                                         WTlo + 2048 * 512, 512, 2048);
  gemm_mfma<2, 1, 0><<<dim3(32, 128), 256, 0, stream>>>(h2, WThi, WTlo, XLR3, nullptr, NN, 4096, 512);
  k_zero<<<NN / 256, 256, 0, stream>>>((float*)menc, NN);
  k_zero<<<NN / 256, 256, 0, stream>>>(ssum, NN);
  k_logits<2048, 4096, bf16><<<(NESL + 3) / 4, 256, 0, stream>>>(XLR3, g3att, srcp, dstp, el, menc);
  k_expsum<<<(NESL + 255) / 256, 256, 0, stream>>>(el, dstp, menc, pbuf, ssum);
  k_agg512<0, 512, 512><<<NN / 2, 256, 0, stream>>>(h2, pbuf, ssum, rowptr, eidx, srcp, nullptr,
                                                    nullptr, agg2);
  // h3 = elu(agg2 @ Wl3 + b3), fp32-grade split, bf16 store (WT first half = Wl3^T)
  gemm_mfma<0, 1, 1><<<dim3(16, 128), 256, 0, stream>>>(agg2, WThi, WTlo, h3, g3b, NN, 2048, 512);
  k_gn_stats<bf16><<<dim3(NG, 8), 256, 0, stream>>>(h3, R, 2048, s1, s2);
  k_gn_apply<bf16><<<(size_t)NN * 2048 / 256, 256, 0, stream>>>(h3, batch, cnt, s1, s2, gn3w,
                                                                gn3b, gn3ms, 2048,
                                                                (size_t)NN * 2048);

  // ---- ARMA1 (2048 -> 512): combined [t1|xwr1] GEMM (bf16 A), agg + relu ----
  k_wsplit<<<(512 * 2048 + 255) / 256, 256, 0, stream>>>(a1wi, WThi, WTlo, 2048, 512);
  k_wsplit<<<(512 * 2048 + 255) / 256, 256, 0, stream>>>(a1wr, WThi + 512 * 2048,
                                                         WTlo + 512 * 2048, 2048, 512);
  gemm_mfma<1, 0, 0><<<dim3(8, 128), 256, 0, stream>>>(h3, WThi, WTlo, TXW1, nullptr, NN, 1024, 2048);
  k_agg512<1, 1024, 512><<<NN / 2, 256, 0, stream>>>(TXW1, normv, nullptr, rowptr, eidx, srcp,
                                                     TXW1, a1b, h4);
  k_gn_stats<float><<<dim3(NG, 2), 256, 0, stream>>>(h4, R, 512, s1, s2);
  k_gn_apply<float><<<(NN * 512 + 255) / 256, 256, 0, stream>>>(h4, batch, cnt, s1, s2, gn4w,
                                                                gn4b, gn4ms, 512, (size_t)NN * 512);

  // ---- ARMA2 (512 -> 64): combined [t2|xwr2] GEMM (fp32 split A), agg + relu ----
  k_wsplit<<<(64 * 512 + 255) / 256, 256, 0, stream>>>(a2wi, WThi, WTlo, 512, 64);
  k_wsplit<<<(64 * 512 + 255) / 256, 256, 0, stream>>>(a2wr, WThi + 64 * 512, WTlo + 64 * 512,
                                                       512, 64);
  gemm_mfma<0, 0, 0><<<dim3(1, 128), 256, 0, stream>>>(h4, WThi, WTlo, TXW2, nullptr, NN, 128, 512);
  k_agg64<1, 128, 64><<<NN / 4, 256, 0, stream>>>(TXW2, normv, nullptr, rowptr, eidx, srcp, TXW2,
                                                  a2b, S2);
  k_gn_stats<float><<<dim3(NG, 1), 64, 0, stream>>>(S2, R, 64, s1, s2);
  k_gn_apply<float><<<(NN * 64 + 255) / 256, 256, 0, stream>>>(S2, batch, cnt, s1, s2, gn5w,
                                                               gn5b, gn5ms, 64, (size_t)NN * 64);

  // ---- pooling + linear ----
  k_pool<<<NG, 64, 0, stream>>>(S2, R, cnt, linw, linb, out);
}

// Round 6
// 1375.058 us; speedup vs baseline: 5.5534x; 1.0984x over previous
//
#include <hip/hip_runtime.h>
#include <hip/hip_bf16.h>

#define NN 16384
#define NE 65536
#define NESL (NE + NN)
#define NG 64

typedef __hip_bfloat16 bf16;
typedef __attribute__((ext_vector_type(8))) short short8v;
typedef __attribute__((ext_vector_type(4))) float f32x4;
typedef __attribute__((address_space(3))) void lds_void;
typedef const __attribute__((address_space(1))) void glb_void;

__device__ __forceinline__ short bfbits(float v) {
  bf16 h = __float2bfloat16(v);
  return *(short*)&h;
}
__device__ __forceinline__ float bfs2f(short s) {
  return __uint_as_float(((unsigned)(unsigned short)s) << 16);
}
__device__ __forceinline__ void gld16(const void* g, void* l) {
  __builtin_amdgcn_global_load_lds((glb_void*)g, (lds_void*)l, 16, 0, 0);
}

// ---------------- utility ----------------
__global__ void k_zero2(int* a, int* b, int n) {
  int i = blockIdx.x * blockDim.x + threadIdx.x;
  if (i < n) { a[i] = 0; b[i] = 0; }
}

// ---------------- graph preprocessing ----------------

__global__ void k_ranges(const int* __restrict__ batch, int* __restrict__ R,
                         float* __restrict__ cnt) {
  int g = threadIdx.x;
  if (g <= NG) {
    int lo = 0, hi = NN;
    while (lo < hi) { int mid = (lo + hi) >> 1; if (batch[mid] < g) lo = mid + 1; else hi = mid; }
    R[g] = lo;
  }
  __syncthreads();
  if (g < NG) cnt[g] = fmaxf((float)(R[g + 1] - R[g]), 1.0f);
}

__global__ void k_deg(const int* __restrict__ dst, int* __restrict__ deg) {
  int e = blockIdx.x * blockDim.x + threadIdx.x;
  if (e < NE) atomicAdd(deg + dst[e], 1);
}

__global__ void k_dis(const int* __restrict__ deg, float* __restrict__ dis) {
  int n = blockIdx.x * blockDim.x + threadIdx.x;
  if (n < NN) { int d = deg[n]; dis[n] = d > 0 ? 1.0f / sqrtf((float)d) : 0.0f; }
}

__global__ void k_scan(const int* __restrict__ deg, int* __restrict__ rowptr) {
  __shared__ int sums[1024];
  int tid = threadIdx.x;
  int base = tid * 16;
  int loc[16];
  int run = 0;
#pragma unroll
  for (int i = 0; i < 16; i++) { run += deg[base + i] + 1; loc[i] = run; }
  sums[tid] = run;
  __syncthreads();
  for (int off = 1; off < 1024; off <<= 1) {
    int v = sums[tid];
    int u = (tid >= off) ? sums[tid - off] : 0;
    __syncthreads();
    sums[tid] = v + u;
    __syncthreads();
  }
  int offset = (tid > 0) ? sums[tid - 1] : 0;
  if (tid == 0) rowptr[0] = 0;
#pragma unroll
  for (int i = 0; i < 16; i++) rowptr[base + i + 1] = loc[i] + offset;
}

// CSR fill: srck = source node per CSR slot, normk = gcn norm (0 for self-loops)
__global__ void k_fill(const int* __restrict__ src, const int* __restrict__ dst,
                       const int* __restrict__ rowptr, const float* __restrict__ dis,
                       int* __restrict__ fill, int* __restrict__ srck,
                       float* __restrict__ normk) {
  int e = blockIdx.x * blockDim.x + threadIdx.x;
  if (e >= NESL) return;
  int s = e < NE ? src[e] : e - NE;
  int d = e < NE ? dst[e] : e - NE;
  int pos = rowptr[d] + atomicAdd(fill + d, 1);
  srck[pos] = s;
  normk[pos] = e < NE ? dis[s] * dis[d] : 0.0f;
}

// ---------------- packed split-bf16 weight prep ----------------
// Packed layout = sequence of 128x32-short tiles, each already the swizzled
// LDS image (tile t = (n>>7)*(K>>5) + (k>>5)).
__device__ __forceinline__ int swz(int row, int kbyte) {
  return ((row << 6) + kbyte) ^ ((row & 7) << 4);
}
__device__ __forceinline__ size_t pidx(int n, int k, int K) {
  size_t t = (size_t)(n >> 7) * (K >> 5) + (k >> 5);
  int r = n & 127, kk = k & 31;
  int b = swz(r, (kk >> 3) << 4) + ((kk & 7) << 1);
  return t * 4096 + (b >> 1);
}

// W [K,N] fp32 -> packed hi/lo at row offset n0 within the combined tensor
__global__ void k_wsplit_pk(const float* __restrict__ w, short* __restrict__ hi,
                            short* __restrict__ lo, int K, int N, int n0) {
  int i = blockIdx.x * blockDim.x + threadIdx.x;
  if (i >= N * K) return;
  int n = i / K, k = i % K;
  float v = w[(size_t)k * N + n];
  short h = bfbits(v);
  size_t pi = pidx(n0 + n, k, K);
  hi[pi] = h;
  lo[pi] = bfbits(v - bfs2f(h));
}

// ---------------- MFMA GEMM ----------------
// C[M,N] = A[M,K] @ Bt[N,K]^T.  128x128 tile, 4 waves, 16x16x32 bf16 MFMA.
// AMODE 0: A fp32, split hi+lo (3 MFMA)   [fp32-grade]
// AMODE 1: A bf16 direct, global_load_lds (2 MFMA)
// AMODE 2: A fp32, hi only (2 MFMA)       [bf16-grade A]
// ACT: 0 none, 1 elu, 2 relu.  CBF16: store bf16 vs f32.

__device__ __forceinline__ void splitw2(const float* ap, char* hidst, char* lodst) {
  f32x4 va = *(const f32x4*)ap;
  f32x4 vb = *(const f32x4*)(ap + 4);
  float f[8] = {va[0], va[1], va[2], va[3], vb[0], vb[1], vb[2], vb[3]};
  short8v h, l;
#pragma unroll
  for (int j = 0; j < 8; j++) {
    short hb = bfbits(f[j]);
    h[j] = hb;
    l[j] = bfbits(f[j] - bfs2f(hb));
  }
  *(short8v*)hidst = h;
  *(short8v*)lodst = l;
}
__device__ __forceinline__ void splitw1(const float* ap, char* hidst) {
  f32x4 va = *(const f32x4*)ap;
  f32x4 vb = *(const f32x4*)(ap + 4);
  float f[8] = {va[0], va[1], va[2], va[3], vb[0], vb[1], vb[2], vb[3]};
  short8v h;
#pragma unroll
  for (int j = 0; j < 8; j++) h[j] = bfbits(f[j]);
  *(short8v*)hidst = h;
}

template <int AMODE, int CBF16, int ACT>
__global__ __launch_bounds__(256) void gemm_mfma(const void* __restrict__ Ap,
                                                 const short* __restrict__ Bthi,
                                                 const short* __restrict__ Btlo,
                                                 void* __restrict__ Cp,
                                                 const float* __restrict__ bias,
                                                 int M, int N, int K) {
  __shared__ __align__(16) short sAhi[128 * 32];
  __shared__ __align__(16) short sAlo[(AMODE == 0) ? 128 * 32 : 16];
  __shared__ __align__(16) short sBhi[128 * 32];
  __shared__ __align__(16) short sBlo[128 * 32];
  const int tid = threadIdx.x;
  const int wave = tid >> 6, lane = tid & 63;
  const int wm = wave >> 1, wn = wave & 1;
  const int row0 = blockIdx.y * 128, col0 = blockIdx.x * 128;
  const int lr = lane & 15;
  const int lkb = (lane >> 4) * 16;  // frag k byte offset within 64B row
  const int nkb = K >> 5;
  f32x4 acc[4][4] = {};

  for (int kb = 0; kb < nkb; kb++) {
    // ---- B staging: direct global->LDS from packed swizzled tiles ----
    {
      const short* bh = Bthi + ((size_t)(col0 >> 7) * nkb + kb) * 4096;
      const short* bl = Btlo + ((size_t)(col0 >> 7) * nkb + kb) * 4096;
      int c = wave * 2;
      gld16(bh + (size_t)c * 512 + lane * 8, (char*)sBhi + c * 1024);
      gld16(bh + (size_t)(c + 1) * 512 + lane * 8, (char*)sBhi + (c + 1) * 1024);
      gld16(bl + (size_t)c * 512 + lane * 8, (char*)sBlo + c * 1024);
      gld16(bl + (size_t)(c + 1) * 512 + lane * 8, (char*)sBlo + (c + 1) * 1024);
    }
    // ---- A staging ----
    if constexpr (AMODE == 1) {
      // gload_lds writes LDS linearly (dest chunk j covers bytes [j*16, j*16+16)).
      // Need LDS[a] = A[swz^{-1}(a)]; swz is NOT an involution (its XOR touches
      // addr bit6 = row bit0), so compute the true inverse:
      //   row  r = ar ^ ((ar>>2)&1)        (undo bit6 mix)
      //   koff   = (c4 ^ (r&3)) * 16      (undo bits 4-5 mix)
      const char* Ab = (const char*)Ap;
#pragma unroll
      for (int ii = 0; ii < 2; ii++) {
        int j = (wave * 2 + ii) * 64 + lane;
        int ar = j >> 2, c4 = j & 3;
        int r = ar ^ ((ar >> 2) & 1);
        int kb2 = (c4 ^ (r & 3)) * 16;
        const char* srcp = Ab + (size_t)(row0 + r) * (K * 2) + kb * 64 + kb2;
        gld16(srcp, (char*)sAhi + (wave * 2 + ii) * 1024);
      }
    } else {
      int r = tid >> 1, kbf = (tid & 1) * 16;
      const float* ap = (const float*)Ap + (size_t)(row0 + r) * K + kb * 32 + kbf;
      int b0 = swz(r, kbf * 2), b1 = swz(r, kbf * 2 + 16);
      if constexpr (AMODE == 0) {
        splitw2(ap, (char*)sAhi + b0, (char*)sAlo + b0);
        splitw2(ap + 8, (char*)sAhi + b1, (char*)sAlo + b1);
      } else {
        splitw1(ap, (char*)sAhi + b0);
        splitw1(ap + 8, (char*)sAhi + b1);
      }
    }
    __syncthreads();
    short8v af[4], al[4], bh[4], bl[4];
#pragma unroll
    for (int f = 0; f < 4; f++) {
      int b = swz(wm * 64 + f * 16 + lr, lkb);
      af[f] = *(short8v*)((char*)sAhi + b);
      if constexpr (AMODE == 0) al[f] = *(short8v*)((char*)sAlo + b);
      int b2 = swz(wn * 64 + f * 16 + lr, lkb);
      bh[f] = *(short8v*)((char*)sBhi + b2);
      bl[f] = *(short8v*)((char*)sBlo + b2);
    }
#pragma unroll
    for (int i = 0; i < 4; i++)
#pragma unroll
      for (int j = 0; j < 4; j++) {
        acc[i][j] = __builtin_amdgcn_mfma_f32_16x16x32_bf16(af[i], bh[j], acc[i][j], 0, 0, 0);
        acc[i][j] = __builtin_amdgcn_mfma_f32_16x16x32_bf16(af[i], bl[j], acc[i][j], 0, 0, 0);
        if constexpr (AMODE == 0)
          acc[i][j] = __builtin_amdgcn_mfma_f32_16x16x32_bf16(al[i], bh[j], acc[i][j], 0, 0, 0);
      }
    __syncthreads();
  }
#pragma unroll
  for (int i = 0; i < 4; i++)
#pragma unroll
    for (int j = 0; j < 4; j++)
#pragma unroll
      for (int r = 0; r < 4; r++) {
        int row = row0 + wm * 64 + i * 16 + ((lane >> 4) << 2) + r;
        int col = col0 + wn * 64 + j * 16 + lr;
        float v = acc[i][j][r];
        if (bias) v += bias[col];
        if constexpr (ACT == 1) v = v > 0.0f ? v : expf(v) - 1.0f;
        if constexpr (ACT == 2) v = fmaxf(v, 0.0f);
        if constexpr (CBF16) {
          ((short*)Cp)[(size_t)row * N + col] = bfbits(v);
        } else {
          ((float*)Cp)[(size_t)row * N + col] = v;
        }
      }
}

// ---------------- GAT1 fused (rank-1): logits + softmax + agg + bias + elu ----------------
__global__ void k_gat1_csr(const float* __restrict__ x, const float* __restrict__ wl,
                           const float* __restrict__ wr, const float* __restrict__ att,
                           const int* __restrict__ rowptr, const int* __restrict__ srck,
                           float* __restrict__ ework, const float* __restrict__ bias,
                           float* __restrict__ out) {
  int node = blockIdx.x * 4 + (threadIdx.x >> 6);
  int lane = threadIdx.x & 63;
  float wlv = wl[lane], wrv = wr[lane], av = att[lane];
  float xd = x[node];
  int beg = rowptr[node], end = rowptr[node + 1];
  float m = -INFINITY;
  for (int k = beg; k < end; k++) {
    float v = x[srck[k]] * wlv + xd * wrv;
    v = v > 0.0f ? v : 0.2f * v;
    float e = av * v;
#pragma unroll
    for (int off = 32; off; off >>= 1) e += __shfl_xor(e, off);
    if (lane == 0) ework[k] = e;
    m = fmaxf(m, e);
  }
  __syncthreads();  // make lane-0 global stores visible to all lanes
  float sum = 0.0f, agg = 0.0f;
  for (int k = beg + lane; k < end; k += 64) {
    float p = expf(ework[k] - m);
    sum += p;
    agg += p * x[srck[k]];
  }
#pragma unroll
  for (int off = 32; off; off >>= 1) {
    sum += __shfl_xor(sum, off);
    agg += __shfl_xor(agg, off);
  }
  float o = agg / (sum + 1e-16f) * wlv + bias[lane];
  out[(size_t)node * 64 + lane] = o > 0.0f ? o : expf(o) - 1.0f;
}

// ---------------- CSR per-node logits + softmax (no atomics) ----------------
// X = [xl | xr] combined, row stride STR; writes pk (CSR order) and ssum.
template <int FO, int STR, typename XT>
__global__ void k_logits_csr(const XT* __restrict__ X, const float* __restrict__ att,
                             const int* __restrict__ rowptr, const int* __restrict__ srck,
                             float* __restrict__ pk, float* __restrict__ ssum) {
  int node = blockIdx.x * 4 + (threadIdx.x >> 6);
  int lane = threadIdx.x & 63;
  constexpr int NV = FO / 64;
  float xr[NV], at[NV];
  if constexpr (sizeof(XT) == 2) {
    const short* xrp = (const short*)X + (size_t)node * STR + FO;
#pragma unroll
    for (int j = 0; j < FO / 512; j++) {
      short8v v = *(const short8v*)(xrp + j * 512 + lane * 8);
      f32x4 a0 = *(const f32x4*)(att + j * 512 + lane * 8);
      f32x4 a1 = *(const f32x4*)(att + j * 512 + lane * 8 + 4);
#pragma unroll
      for (int t = 0; t < 8; t++) {
        xr[j * 8 + t] = bfs2f(v[t]);
        at[j * 8 + t] = t < 4 ? a0[t] : a1[t - 4];
      }
    }
  } else {
    const float* xrp = (const float*)X + (size_t)node * STR + FO;
#pragma unroll
    for (int j = 0; j < FO / 256; j++) {
      f32x4 v = *(const f32x4*)(xrp + j * 256 + lane * 4);
      f32x4 a = *(const f32x4*)(att + j * 256 + lane * 4);
#pragma unroll
      for (int t = 0; t < 4; t++) {
        xr[j * 4 + t] = v[t];
        at[j * 4 + t] = a[t];
      }
    }
  }
  int beg = rowptr[node], end = rowptr[node + 1];
  float m = -INFINITY;
  for (int k = beg; k < end; k++) {
    int s = srck[k];
    float acc = 0.0f;
    if constexpr (sizeof(XT) == 2) {
      const short* xlp = (const short*)X + (size_t)s * STR;
#pragma unroll
      for (int j = 0; j < FO / 512; j++) {
        short8v v = *(const short8v*)(xlp + j * 512 + lane * 8);
#pragma unroll
        for (int t = 0; t < 8; t++) {
          float u = bfs2f(v[t]) + xr[j * 8 + t];
          u = u > 0.0f ? u : 0.2f * u;
          acc += at[j * 8 + t] * u;
        }
      }
    } else {
      const float* xlp = (const float*)X + (size_t)s * STR;
#pragma unroll
      for (int j = 0; j < FO / 256; j++) {
        f32x4 v = *(const f32x4*)(xlp + j * 256 + lane * 4);
#pragma unroll
        for (int t = 0; t < 4; t++) {
          float u = v[t] + xr[j * 4 + t];
          u = u > 0.0f ? u : 0.2f * u;
          acc += at[j * 4 + t] * u;
        }
      }
    }
#pragma unroll
    for (int off = 32; off; off >>= 1) acc += __shfl_xor(acc, off);
    if (lane == 0) pk[k] = acc;
    m = fmaxf(m, acc);
  }
  __syncthreads();  // make lane-0 global stores visible to all lanes
  float sum = 0.0f;
  for (int k = beg + lane; k < end; k += 64) {
    float p = expf(pk[k] - m);
    pk[k] = p;
    sum += p;
  }
#pragma unroll
  for (int off = 32; off; off >>= 1) sum += __shfl_xor(sum, off);
  if (lane == 0) ssum[node] = sum;
}

// ---------------- gather-aggregation (CSR-sequential weights) ----------------
// MODE 0: GAT softmax-weighted; MODE 1: ARMA norm-weighted (+ xwr + bias, relu).
template <int MODE, int SSTR, int OSTR>
__global__ void k_agg512(const float* __restrict__ Xsrc, const float* __restrict__ pk,
                         const float* __restrict__ ssum, const int* __restrict__ rowptr,
                         const int* __restrict__ srck, const float* __restrict__ normk,
                         const float* __restrict__ xwrb, const float* __restrict__ bias,
                         float* __restrict__ out) {
  int wave = threadIdx.x >> 6;
  int node = blockIdx.x * 2 + (wave >> 1);
  int lane = threadIdx.x & 63;
  int c0 = (wave & 1) * 256 + lane * 4;
  f32x4 acc = {};
  int beg = rowptr[node], end = rowptr[node + 1];
  float inv = (MODE == 0) ? 1.0f / (ssum[node] + 1e-16f) : 1.0f;
  for (int k = beg; k < end; k++) {
    int s = srck[k];
    float w = (MODE == 0) ? pk[k] * inv : normk[k];
    f32x4 v = *(const f32x4*)(Xsrc + (size_t)s * SSTR + c0);
#pragma unroll
    for (int t = 0; t < 4; t++) acc[t] += w * v[t];
  }
  if constexpr (MODE == 1) {
    f32x4 xv = *(const f32x4*)(xwrb + (size_t)node * SSTR + 512 + c0);
#pragma unroll
    for (int t = 0; t < 4; t++) acc[t] = fmaxf(acc[t] + xv[t] + bias[c0 + t], 0.0f);
  }
  *(f32x4*)(out + (size_t)node * OSTR + c0) = acc;
}

template <int MODE, int SSTR, int XOFF>
__global__ void k_agg64(const float* __restrict__ Xsrc, const float* __restrict__ pk,
                        const float* __restrict__ ssum, const int* __restrict__ rowptr,
                        const int* __restrict__ srck, const float* __restrict__ normk,
                        const float* __restrict__ xwrb, const float* __restrict__ bias,
                        float* __restrict__ out) {
  int node = blockIdx.x * (blockDim.x >> 6) + (threadIdx.x >> 6);
  if (node >= NN) return;
  int lane = threadIdx.x & 63;
  int cg = lane & 15, eg = lane >> 4;
  int c0 = cg * 4;
  f32x4 acc = {};
  int beg = rowptr[node], end = rowptr[node + 1];
  float inv = (MODE == 0) ? 1.0f / (ssum[node] + 1e-16f) : 1.0f;
  for (int k = beg + eg; k < end; k += 4) {
    int s = srck[k];
    float w = (MODE == 0) ? pk[k] * inv : normk[k];
    f32x4 v = *(const f32x4*)(Xsrc + (size_t)s * SSTR + c0);
#pragma unroll
    for (int t = 0; t < 4; t++) acc[t] += w * v[t];
  }
#pragma unroll
  for (int t = 0; t < 4; t++) {
    acc[t] += __shfl_xor(acc[t], 16);
    acc[t] += __shfl_xor(acc[t], 32);
  }
  if (eg == 0) {
    if constexpr (MODE == 1) {
      f32x4 xv = *(const f32x4*)(xwrb + (size_t)node * SSTR + XOFF + c0);
#pragma unroll
      for (int t = 0; t < 4; t++) acc[t] = fmaxf(acc[t] + xv[t] + bias[c0 + t], 0.0f);
    }
    *(f32x4*)(out + (size_t)node * 64 + c0) = acc;
  }
}

// ---------------- GraphNorm (vectorized) ----------------
// VEC = 8 for bf16, 4 for f32.
template <typename T, int VEC>
__global__ void k_gn_stats_v(const T* __restrict__ x, const int* __restrict__ R, int C,
                             float* __restrict__ s1, float* __restrict__ s2) {
  int g = blockIdx.x;
  int c0 = (blockIdx.y * blockDim.x + threadIdx.x) * VEC;
  if (c0 >= C) return;
  int beg = R[g], end = R[g + 1];
  float a[VEC] = {}, b[VEC] = {};
  for (int n = beg; n < end; n++) {
    const T* p = x + (size_t)n * C + c0;
    float v[VEC];
    if constexpr (sizeof(T) == 2) {
      short8v h = *(const short8v*)p;
#pragma unroll
      for (int t = 0; t < VEC; t++) v[t] = bfs2f(h[t]);
    } else {
      f32x4 h = *(const f32x4*)p;
#pragma unroll
      for (int t = 0; t < VEC; t++) v[t] = h[t];
    }
#pragma unroll
    for (int t = 0; t < VEC; t++) {
      a[t] += v[t];
      b[t] += v[t] * v[t];
    }
  }
#pragma unroll
  for (int t = 0; t < VEC; t++) {
    s1[g * C + c0 + t] = a[t];
    s2[g * C + c0 + t] = b[t];
  }
}

template <typename T, int VEC>
__global__ void k_gn_apply_v(T* __restrict__ x, const int* __restrict__ batch,
                             const float* __restrict__ cnt, const float* __restrict__ s1,
                             const float* __restrict__ s2, const float* __restrict__ w,
                             const float* __restrict__ b, const float* __restrict__ ms, int C,
                             int total_vec) {
  int i = blockIdx.x * blockDim.x + threadIdx.x;
  if (i >= total_vec) return;
  int cpv = C / VEC;
  int n = i / cpv, c0 = (i % cpv) * VEC;
  int g = batch[n];
  float ct = cnt[g];
  T* p = x + (size_t)n * C + c0;
  float v[VEC];
  if constexpr (sizeof(T) == 2) {
    short8v h = *(const short8v*)p;
#pragma unroll
    for (int t = 0; t < VEC; t++) v[t] = bfs2f(h[t]);
  } else {
    f32x4 h = *(const f32x4*)p;
#pragma unroll
    for (int t = 0; t < VEC; t++) v[t] = h[t];
  }
#pragma unroll
  for (int t = 0; t < VEC; t++) {
    int c = c0 + t;
    float mean = s1[g * C + c] / ct;
    float mm = mean * ms[c];
    float var = s2[g * C + c] / ct - 2.0f * mm * mean + mm * mm;
    v[t] = (v[t] - mm) * (1.0f / sqrtf(var + 1e-5f)) * w[c] + b[c];
  }
  if constexpr (sizeof(T) == 2) {
    short8v h;
#pragma unroll
    for (int t = 0; t < VEC; t++) h[t] = bfbits(v[t]);
    *(short8v*)p = h;
  } else {
    f32x4 h;
#pragma unroll
    for (int t = 0; t < VEC; t++) h[t] = v[t];
    *(f32x4*)p = h;
  }
}

// ---------------- pooling + final linear ----------------

__global__ void k_pool(const float* __restrict__ h, const int* __restrict__ R,
                       const float* __restrict__ cnt, const float* __restrict__ lw,
                       const float* __restrict__ lb, float* __restrict__ out) {
  int g = blockIdx.x;
  int c = threadIdx.x;  // 64
  int beg = R[g], end = R[g + 1];
  float mx = -INFINITY, sm = 0.0f;
  for (int n = beg; n < end; n++) {
    float v = h[(size_t)n * 64 + c];
    mx = fmaxf(mx, v);
    sm += v;
  }
  __shared__ float feat[192];
  feat[c] = mx;
  feat[64 + c] = sm / cnt[g];
  feat[128 + c] = sm;
  __syncthreads();
  if (c < 2) {
    float acc = lb[c];
    for (int j = 0; j < 192; j++) acc += feat[j] * lw[j * 2 + c];
    out[g * 2 + c] = acc;
  }
}

// ---------------- launch ----------------

extern "C" void kernel_launch(void* const* d_in, const int* in_sizes, int n_in,
                              void* d_out, int out_size, void* d_ws, size_t ws_size,
                              hipStream_t stream) {
  const float* x = (const float*)d_in[0];
  const int* ei = (const int*)d_in[1];
  const int* batch = (const int*)d_in[2];
  const float* g1wl = (const float*)d_in[3];
  const float* g1wr = (const float*)d_in[4];
  const float* g1att = (const float*)d_in[5];
  const float* g1b = (const float*)d_in[6];
  const float* g2wl = (const float*)d_in[7];
  const float* g2wr = (const float*)d_in[8];
  const float* g2att = (const float*)d_in[9];
  const float* g2b = (const float*)d_in[10];
  const float* g3wl = (const float*)d_in[11];
  const float* g3wr = (const float*)d_in[12];
  const float* g3att = (const float*)d_in[13];
  const float* g3b = (const float*)d_in[14];
  const float* gn1w = (const float*)d_in[15];
  const float* gn1b = (const float*)d_in[16];
  const float* gn1ms = (const float*)d_in[17];
  const float* gn2w = (const float*)d_in[18];
  const float* gn2b = (const float*)d_in[19];
  const float* gn2ms = (const float*)d_in[20];
  const float* gn3w = (const float*)d_in[21];
  const float* gn3b = (const float*)d_in[22];
  const float* gn3ms = (const float*)d_in[23];
  const float* gn4w = (const float*)d_in[24];
  const float* gn4b = (const float*)d_in[25];
  const float* gn4ms = (const float*)d_in[26];
  const float* gn5w = (const float*)d_in[27];
  const float* gn5b = (const float*)d_in[28];
  const float* gn5ms = (const float*)d_in[29];
  const float* a1wi = (const float*)d_in[30];
  const float* a1wr = (const float*)d_in[31];
  const float* a1b = (const float*)d_in[32];
  const float* a2wi = (const float*)d_in[33];
  const float* a2wr = (const float*)d_in[34];
  const float* a2b = (const float*)d_in[35];
  const float* linw = (const float*)d_in[36];
  const float* linb = (const float*)d_in[37];
  const int* srcp = ei;
  const int* dstp = ei + NE;
  float* out = (float*)d_out;

  float* ws = (float*)d_ws;
  size_t o = 0;
  auto alloc = [&](size_t nfloats) { float* p = ws + o; o += nfloats; return p; };
  float* BIG0f = alloc((size_t)NN * 1024);  // 64 MB
  float* BIG1f = alloc((size_t)NN * 1024);  // 64 MB
  float* B0 = alloc((size_t)NN * 512);      // 32 MB
  float* B1 = alloc((size_t)NN * 512);      // 32 MB
  float* h1 = alloc((size_t)NN * 64);
  float* aggS = alloc((size_t)NN * 64);
  float* S0 = alloc((size_t)NN * 64);  // [t2|xwr2] spans S0+S1
  float* S1 = alloc((size_t)NN * 64);
  float* S2 = alloc((size_t)NN * 64);  // h5
  float* pk = alloc(NESL);
  float* normk = alloc(NESL);
  float* ssum = alloc(NN);
  float* dis = alloc(NN);
  float* cnt = alloc(NG);
  float* s1 = alloc(NG * 2048);
  float* s2 = alloc(NG * 2048);
  short* WThi = (short*)alloc((size_t)4096 * 512 / 2);  // 4 MB packed tiles
  short* WTlo = (short*)alloc((size_t)4096 * 512 / 2);
  int* deg = (int*)alloc(NN);
  int* rowptr = (int*)alloc(NN + 1);
  int* fill = (int*)alloc(NN);
  int* srck = (int*)alloc(NESL);
  int* R = (int*)alloc(72);

  bf16* XLR3 = (bf16*)BIG0f;  // [NN][4096] bf16 (spans BIG0f+BIG1f)
  bf16* h3 = (bf16*)BIG0f;    // [NN][2048] bf16 (after XLR3 dead)
  float* h4 = BIG1f;          // [NN][512] f32 (after XLR3 dead)
  float* XLR2 = B0;           // [NN][1024] f32 (spans B0+B1)
  float* h2 = B0;             // [NN][512] f32
  float* agg2 = B1;           // [NN][512] f32
  float* TXW1 = B0;           // [t1|xwr1] [NN][1024] f32
  float* TXW2 = S0;           // [t2|xwr2] [NN][128] f32

  // ---- preprocessing ----
  k_zero2<<<NN / 256, 256, 0, stream>>>(deg, fill, NN);
  k_ranges<<<1, 128, 0, stream>>>(batch, R, cnt);
  k_deg<<<NE / 256, 256, 0, stream>>>(dstp, deg);
  k_scan<<<1, 1024, 0, stream>>>(deg, rowptr);
  k_dis<<<NN / 256, 256, 0, stream>>>(deg, dis);
  k_fill<<<(NESL + 255) / 256, 256, 0, stream>>>(srcp, dstp, rowptr, dis, fill, srck, normk);

  // ---- GAT1 (1 -> 64, rank-1, fused) ----
  k_gat1_csr<<<NN / 4, 256, 0, stream>>>(x, g1wl, g1wr, g1att, rowptr, srck, pk, g1b, h1);
  k_gn_stats_v<float, 4><<<dim3(NG, 1), 16, 0, stream>>>(h1, R, 64, s1, s2);
  k_gn_apply_v<float, 4><<<NN * 16 / 256, 256, 0, stream>>>(h1, batch, cnt, s1, s2, gn1w, gn1b,
                                                            gn1ms, 64, NN * 16);

  // ---- GAT2 (64 -> 512): combined [xl2|xr2] GEMM, agg in 64-space, project ----
  k_wsplit_pk<<<(512 * 64 + 255) / 256, 256, 0, stream>>>(g2wl, WThi, WTlo, 64, 512, 0);
  k_wsplit_pk<<<(512 * 64 + 255) / 256, 256, 0, stream>>>(g2wr, WThi, WTlo, 64, 512, 512);
  gemm_mfma<0, 0, 0><<<dim3(8, 128), 256, 0, stream>>>(h1, WThi, WTlo, XLR2, nullptr, NN, 1024, 64);
  k_logits_csr<512, 1024, float><<<NN / 4, 256, 0, stream>>>(XLR2, g2att, rowptr, srck, pk, ssum);
  k_agg64<0, 64, 0><<<NN / 4, 256, 0, stream>>>(h1, pk, ssum, rowptr, srck, normk, nullptr,
                                                nullptr, aggS);
  gemm_mfma<0, 0, 1><<<dim3(4, 128), 256, 0, stream>>>(aggS, WThi, WTlo, h2, g2b, NN, 512, 64);
  k_gn_stats_v<float, 4><<<dim3(NG, 1), 128, 0, stream>>>(h2, R, 512, s1, s2);
  k_gn_apply_v<float, 4><<<NN * 128 / 256, 256, 0, stream>>>(h2, batch, cnt, s1, s2, gn2w, gn2b,
                                                             gn2ms, 512, NN * 128);

  // ---- GAT3 (512 -> 2048): combined [xl3|xr3] bf16, agg in 512-space, split-project ----
  k_wsplit_pk<<<(2048 * 512 + 255) / 256, 256, 0, stream>>>(g3wl, WThi, WTlo, 512, 2048, 0);
  k_wsplit_pk<<<(2048 * 512 + 255) / 256, 256, 0, stream>>>(g3wr, WThi, WTlo, 512, 2048, 2048);
  gemm_mfma<2, 1, 0><<<dim3(32, 128), 256, 0, stream>>>(h2, WThi, WTlo, XLR3, nullptr, NN, 4096, 512);
  k_logits_csr<2048, 4096, bf16><<<NN / 4, 256, 0, stream>>>(XLR3, g3att, rowptr, srck, pk, ssum);
  k_agg512<0, 512, 512><<<NN / 2, 256, 0, stream>>>(h2, pk, ssum, rowptr, srck, normk, nullptr,
                                                    nullptr, agg2);
  gemm_mfma<0, 1, 1><<<dim3(16, 128), 256, 0, stream>>>(agg2, WThi, WTlo, h3, g3b, NN, 2048, 512);
  k_gn_stats_v<bf16, 8><<<dim3(NG, 1), 256, 0, stream>>>(h3, R, 2048, s1, s2);
  k_gn_apply_v<bf16, 8><<<NN * 256 / 256, 256, 0, stream>>>(h3, batch, cnt, s1, s2, gn3w, gn3b,
                                                            gn3ms, 2048, NN * 256);

  // ---- ARMA1 (2048 -> 512): combined [t1|xwr1] GEMM (bf16 A via gload), agg + relu ----
  k_wsplit_pk<<<(512 * 2048 + 255) / 256, 256, 0, stream>>>(a1wi, WThi, WTlo, 2048, 512, 0);
  k_wsplit_pk<<<(512 * 2048 + 255) / 256, 256, 0, stream>>>(a1wr, WThi, WTlo, 2048, 512, 512);
  gemm_mfma<1, 0, 0><<<dim3(8, 128), 256, 0, stream>>>(h3, WThi, WTlo, TXW1, nullptr, NN, 1024, 2048);
  k_agg512<1, 1024, 512><<<NN / 2, 256, 0, stream>>>(TXW1, pk, nullptr, rowptr, srck, normk,
                                                     TXW1, a1b, h4);
  k_gn_stats_v<float, 4><<<dim3(NG, 1), 128, 0, stream>>>(h4, R, 512, s1, s2);
  k_gn_apply_v<float, 4><<<NN * 128 / 256, 256, 0, stream>>>(h4, batch, cnt, s1, s2, gn4w, gn4b,
                                                             gn4ms, 512, NN * 128);

  // ---- ARMA2 (512 -> 64): combined [t2|xwr2] GEMM, agg + relu ----
  k_wsplit_pk<<<(64 * 512 + 255) / 256, 256, 0, stream>>>(a2wi, WThi, WTlo, 512, 64, 0);
  k_wsplit_pk<<<(64 * 512 + 255) / 256, 256, 0, stream>>>(a2wr, WThi, WTlo, 512, 64, 64);
  gemm_mfma<0, 0, 0><<<dim3(1, 128), 256, 0, stream>>>(h4, WThi, WTlo, TXW2, nullptr, NN, 128, 512);
  k_agg64<1, 128, 64><<<NN / 4, 256, 0, stream>>>(TXW2, pk, nullptr, rowptr, srck, normk, TXW2,
                                                  a2b, S2);
  k_gn_stats_v<float, 4><<<dim3(NG, 1), 16, 0, stream>>>(S2, R, 64, s1, s2);
  k_gn_apply_v<float, 4><<<NN * 16 / 256, 256, 0, stream>>>(S2, batch, cnt, s1, s2, gn5w, gn5b,
                                                            gn5ms, 64, NN * 16);

  // ---- pooling + linear ----
  k_pool<<<NG, 64, 0, stream>>>(S2, R, cnt, linw, linb, out);
}

// Round 7
// 1303.385 us; speedup vs baseline: 5.8588x; 1.0550x over previous
//
#include <hip/hip_runtime.h>
#include <hip/hip_bf16.h>

#define NN 16384
#define NE 65536
#define NESL (NE + NN)
#define NG 64

typedef __hip_bfloat16 bf16;
typedef __attribute__((ext_vector_type(8))) short short8v;
typedef __attribute__((ext_vector_type(4))) float f32x4;
typedef __attribute__((address_space(3))) void lds_void;
typedef const __attribute__((address_space(1))) void glb_void;

__device__ __forceinline__ short bfbits(float v) {
  bf16 h = __float2bfloat16(v);
  return *(short*)&h;
}
__device__ __forceinline__ float bfs2f(short s) {
  return __uint_as_float(((unsigned)(unsigned short)s) << 16);
}
__device__ __forceinline__ void gld16(const void* g, void* l) {
  __builtin_amdgcn_global_load_lds((glb_void*)g, (lds_void*)l, 16, 0, 0);
}

// ---------------- utility ----------------
__global__ void k_zero2(int* a, int* b, int n) {
  int i = blockIdx.x * blockDim.x + threadIdx.x;
  if (i < n) { a[i] = 0; b[i] = 0; }
}

// ---------------- graph preprocessing ----------------

__global__ void k_ranges(const int* __restrict__ batch, int* __restrict__ R,
                         float* __restrict__ cnt) {
  int g = threadIdx.x;
  if (g <= NG) {
    int lo = 0, hi = NN;
    while (lo < hi) { int mid = (lo + hi) >> 1; if (batch[mid] < g) lo = mid + 1; else hi = mid; }
    R[g] = lo;
  }
  __syncthreads();
  if (g < NG) cnt[g] = fmaxf((float)(R[g + 1] - R[g]), 1.0f);
}

__global__ void k_deg(const int* __restrict__ dst, int* __restrict__ deg) {
  int e = blockIdx.x * blockDim.x + threadIdx.x;
  if (e < NE) atomicAdd(deg + dst[e], 1);
}

__global__ void k_dis(const int* __restrict__ deg, float* __restrict__ dis) {
  int n = blockIdx.x * blockDim.x + threadIdx.x;
  if (n < NN) { int d = deg[n]; dis[n] = d > 0 ? 1.0f / sqrtf((float)d) : 0.0f; }
}

__global__ void k_scan(const int* __restrict__ deg, int* __restrict__ rowptr) {
  __shared__ int sums[1024];
  int tid = threadIdx.x;
  int base = tid * 16;
  int loc[16];
  int run = 0;
#pragma unroll
  for (int i = 0; i < 16; i++) { run += deg[base + i] + 1; loc[i] = run; }
  sums[tid] = run;
  __syncthreads();
  for (int off = 1; off < 1024; off <<= 1) {
    int v = sums[tid];
    int u = (tid >= off) ? sums[tid - off] : 0;
    __syncthreads();
    sums[tid] = v + u;
    __syncthreads();
  }
  int offset = (tid > 0) ? sums[tid - 1] : 0;
  if (tid == 0) rowptr[0] = 0;
#pragma unroll
  for (int i = 0; i < 16; i++) rowptr[base + i + 1] = loc[i] + offset;
}

// CSR fill: srck = source node per CSR slot, normk = gcn norm (0 for self-loops)
__global__ void k_fill(const int* __restrict__ src, const int* __restrict__ dst,
                       const int* __restrict__ rowptr, const float* __restrict__ dis,
                       int* __restrict__ fill, int* __restrict__ srck,
                       float* __restrict__ normk) {
  int e = blockIdx.x * blockDim.x + threadIdx.x;
  if (e >= NESL) return;
  int s = e < NE ? src[e] : e - NE;
  int d = e < NE ? dst[e] : e - NE;
  int pos = rowptr[d] + atomicAdd(fill + d, 1);
  srck[pos] = s;
  normk[pos] = e < NE ? dis[s] * dis[d] : 0.0f;
}

// ---------------- packed split-bf16 weight prep ----------------
// Packed tile format (128 cols x 32 k, 4096 shorts): FRAGMENT-LINEAR.
// chunk c (0..7) = col-group c (cols c*16..c*16+15); within chunk, lane
// l = (k>>3)*16 | (col&15) holds 8 shorts (k&7). A gld16 of chunk c with
// per-lane src "+lane*8" stages it so a wave's frag read is base+lane*16
// -> linear, conflict-free.
__device__ __forceinline__ size_t pidx(int n, int k, int K) {
  size_t t = (size_t)(n >> 7) * (K >> 5) + (k >> 5);
  int col = n & 127, kk = k & 31;
  int lane = ((kk >> 3) << 4) | (col & 15);
  return t * 4096 + (size_t)((col >> 4) * 512 + lane * 8 + (kk & 7));
}

// W [K,N] fp32 -> packed hi/lo at row offset n0 within the combined tensor
__global__ void k_wsplit_pk(const float* __restrict__ w, short* __restrict__ hi,
                            short* __restrict__ lo, int K, int N, int n0) {
  int i = blockIdx.x * blockDim.x + threadIdx.x;
  if (i >= N * K) return;
  int n = i / K, k = i % K;
  float v = w[(size_t)k * N + n];
  short h = bfbits(v);
  size_t pi = pidx(n0 + n, k, K);
  hi[pi] = h;
  lo[pi] = bfbits(v - bfs2f(h));
}

// ---------------- MFMA GEMM (fp32-split A, reg-staged) ----------------
// C[M,N] = A[M,K] @ Bt[N,K]^T.  128x128 tile, 4 waves, 16x16x32 bf16 MFMA.
// A fp32 split hi+lo in-kernel (3 MFMA, fp32-grade).  B packed frag-linear.
__device__ __forceinline__ int swz(int row, int kbyte) {
  return ((row << 6) + kbyte) ^ ((row & 7) << 4);
}

__device__ __forceinline__ void splitw2(const float* ap, char* hidst, char* lodst) {
  f32x4 va = *(const f32x4*)ap;
  f32x4 vb = *(const f32x4*)(ap + 4);
  float f[8] = {va[0], va[1], va[2], va[3], vb[0], vb[1], vb[2], vb[3]};
  short8v h, l;
#pragma unroll
  for (int j = 0; j < 8; j++) {
    short hb = bfbits(f[j]);
    h[j] = hb;
    l[j] = bfbits(f[j] - bfs2f(hb));
  }
  *(short8v*)hidst = h;
  *(short8v*)lodst = l;
}

template <int CBF16, int ACT>
__global__ __launch_bounds__(256) void gemm_mfma_s(const float* __restrict__ Ap,
                                                   const short* __restrict__ Bthi,
                                                   const short* __restrict__ Btlo,
                                                   void* __restrict__ Cp,
                                                   const float* __restrict__ bias,
                                                   int M, int N, int K) {
  __shared__ __align__(16) short sAhi[128 * 32];
  __shared__ __align__(16) short sAlo[128 * 32];
  __shared__ __align__(16) short sBhi[128 * 32];
  __shared__ __align__(16) short sBlo[128 * 32];
  const int tid = threadIdx.x;
  const int wave = tid >> 6, lane = tid & 63;
  const int wm = wave >> 1, wn = wave & 1;
  const int row0 = blockIdx.y * 128, col0 = blockIdx.x * 128;
  const int lr = lane & 15;
  const int lkb = (lane >> 4) * 16;
  const int nkb = K >> 5;
  f32x4 acc[4][4] = {};

  for (int kb = 0; kb < nkb; kb++) {
    {  // B staging: binary copy of frag-linear packed tile
      const short* bh = Bthi + ((size_t)(col0 >> 7) * nkb + kb) * 4096;
      const short* bl = Btlo + ((size_t)(col0 >> 7) * nkb + kb) * 4096;
      int c = wave * 2;
      gld16(bh + (size_t)c * 512 + lane * 8, (char*)sBhi + c * 1024);
      gld16(bh + (size_t)(c + 1) * 512 + lane * 8, (char*)sBhi + (c + 1) * 1024);
      gld16(bl + (size_t)c * 512 + lane * 8, (char*)sBlo + c * 1024);
      gld16(bl + (size_t)(c + 1) * 512 + lane * 8, (char*)sBlo + (c + 1) * 1024);
    }
    {  // A staging: load fp32, split to hi/lo bf16 (swizzled row-major layout)
      int r = tid >> 1, kbf = (tid & 1) * 16;
      const float* ap = Ap + (size_t)(row0 + r) * K + kb * 32 + kbf;
      int b0 = swz(r, kbf * 2), b1 = swz(r, kbf * 2 + 16);
      splitw2(ap, (char*)sAhi + b0, (char*)sAlo + b0);
      splitw2(ap + 8, (char*)sAhi + b1, (char*)sAlo + b1);
    }
    __syncthreads();
    short8v af[4], al[4], bh[4], bl[4];
#pragma unroll
    for (int f = 0; f < 4; f++) {
      int b = swz(wm * 64 + f * 16 + lr, lkb);
      af[f] = *(short8v*)((char*)sAhi + b);
      al[f] = *(short8v*)((char*)sAlo + b);
      int b2 = (wn * 4 + f) * 1024 + lane * 16;  // frag-linear B
      bh[f] = *(short8v*)((char*)sBhi + b2);
      bl[f] = *(short8v*)((char*)sBlo + b2);
    }
#pragma unroll
    for (int i = 0; i < 4; i++)
#pragma unroll
      for (int j = 0; j < 4; j++) {
        acc[i][j] = __builtin_amdgcn_mfma_f32_16x16x32_bf16(af[i], bh[j], acc[i][j], 0, 0, 0);
        acc[i][j] = __builtin_amdgcn_mfma_f32_16x16x32_bf16(af[i], bl[j], acc[i][j], 0, 0, 0);
        acc[i][j] = __builtin_amdgcn_mfma_f32_16x16x32_bf16(al[i], bh[j], acc[i][j], 0, 0, 0);
      }
    __syncthreads();
  }
#pragma unroll
  for (int i = 0; i < 4; i++)
#pragma unroll
    for (int j = 0; j < 4; j++)
#pragma unroll
      for (int r = 0; r < 4; r++) {
        int row = row0 + wm * 64 + i * 16 + ((lane >> 4) << 2) + r;
        int col = col0 + wn * 64 + j * 16 + lr;
        float v = acc[i][j][r];
        if (bias) v += bias[col];
        if constexpr (ACT == 1) v = v > 0.0f ? v : expf(v) - 1.0f;
        if constexpr (ACT == 2) v = fmaxf(v, 0.0f);
        if constexpr (CBF16) {
          ((short*)Cp)[(size_t)row * N + col] = bfbits(v);
        } else {
          ((float*)Cp)[(size_t)row * N + col] = v;
        }
      }
}

// ---------------- MFMA GEMM (bf16-plane A, all-gld16, 2-phase pipelined) ----
// A: [M][K] bf16 row-major plane.  B: packed frag-linear hi+lo.
// Double-buffered LDS; counted vmcnt(6) keeps next tile's 6 loads in flight.
template <int CBF16, int ACT>
__global__ __launch_bounds__(256) void gemm_mfma_p(const short* __restrict__ A,
                                                   const short* __restrict__ Bthi,
                                                   const short* __restrict__ Btlo,
                                                   void* __restrict__ Cp,
                                                   const float* __restrict__ bias,
                                                   int M, int N, int K) {
  __shared__ __align__(16) short sA[2][4096];
  __shared__ __align__(16) short sB[2][8192];
  const int tid = threadIdx.x;
  const int wave = tid >> 6, lane = tid & 63;
  const int wm = wave >> 1, wn = wave & 1;
  const int row0 = blockIdx.y * 128, col0 = blockIdx.x * 128;
  const int nkb = K >> 5;
  const int c = wave * 2;
  const int ar = lane & 15, akc = lane >> 4;
  f32x4 acc[4][4] = {};

  auto stage = [&](int buf, int kb) {
    const short* bh = Bthi + ((size_t)(col0 >> 7) * nkb + kb) * 4096;
    const short* bl = Btlo + ((size_t)(col0 >> 7) * nkb + kb) * 4096;
    gld16(bh + (size_t)c * 512 + lane * 8, (char*)sB[buf] + c * 1024);
    gld16(bh + (size_t)(c + 1) * 512 + lane * 8, (char*)sB[buf] + (c + 1) * 1024);
    gld16(bl + (size_t)c * 512 + lane * 8, (char*)sB[buf] + 8192 + c * 1024);
    gld16(bl + (size_t)(c + 1) * 512 + lane * 8, (char*)sB[buf] + 8192 + (c + 1) * 1024);
    gld16(A + (size_t)(row0 + c * 16 + ar) * K + kb * 32 + akc * 8,
          (char*)sA[buf] + c * 1024);
    gld16(A + (size_t)(row0 + (c + 1) * 16 + ar) * K + kb * 32 + akc * 8,
          (char*)sA[buf] + (c + 1) * 1024);
  };

  stage(0, 0);
  for (int kb = 0; kb < nkb; kb++) {
    int cur = kb & 1;
    if (kb + 1 < nkb) {
      stage(cur ^ 1, kb + 1);
      asm volatile("s_waitcnt vmcnt(6)" ::: "memory");
    } else {
      asm volatile("s_waitcnt vmcnt(0)" ::: "memory");
    }
    __builtin_amdgcn_s_barrier();
    short8v af[4], bh[4], bl[4];
#pragma unroll
    for (int f = 0; f < 4; f++) {
      af[f] = *(short8v*)((char*)sA[cur] + (wm * 4 + f) * 1024 + lane * 16);
      bh[f] = *(short8v*)((char*)sB[cur] + (wn * 4 + f) * 1024 + lane * 16);
      bl[f] = *(short8v*)((char*)sB[cur] + 8192 + (wn * 4 + f) * 1024 + lane * 16);
    }
#pragma unroll
    for (int i = 0; i < 4; i++)
#pragma unroll
      for (int j = 0; j < 4; j++) {
        acc[i][j] = __builtin_amdgcn_mfma_f32_16x16x32_bf16(af[i], bh[j], acc[i][j], 0, 0, 0);
        acc[i][j] = __builtin_amdgcn_mfma_f32_16x16x32_bf16(af[i], bl[j], acc[i][j], 0, 0, 0);
      }
    __builtin_amdgcn_s_barrier();
  }
#pragma unroll
  for (int i = 0; i < 4; i++)
#pragma unroll
    for (int j = 0; j < 4; j++)
#pragma unroll
      for (int r = 0; r < 4; r++) {
        int row = row0 + wm * 64 + i * 16 + ((lane >> 4) << 2) + r;
        int col = col0 + wn * 64 + j * 16 + (lane & 15);
        float v = acc[i][j][r];
        if (bias) v += bias[col];
        if constexpr (ACT == 1) v = v > 0.0f ? v : expf(v) - 1.0f;
        if constexpr (ACT == 2) v = fmaxf(v, 0.0f);
        if constexpr (CBF16) {
          ((short*)Cp)[(size_t)row * N + col] = bfbits(v);
        } else {
          ((float*)Cp)[(size_t)row * N + col] = v;
        }
      }
}

// ---------------- GAT1 fused (rank-1) ----------------
__global__ void k_gat1_csr(const float* __restrict__ x, const float* __restrict__ wl,
                           const float* __restrict__ wr, const float* __restrict__ att,
                           const int* __restrict__ rowptr, const int* __restrict__ srck,
                           float* __restrict__ ework, const float* __restrict__ bias,
                           float* __restrict__ out) {
  int node = blockIdx.x * 4 + (threadIdx.x >> 6);
  int lane = threadIdx.x & 63;
  float wlv = wl[lane], wrv = wr[lane], av = att[lane];
  float xd = x[node];
  int beg = rowptr[node], end = rowptr[node + 1];
  float m = -INFINITY;
  for (int k = beg; k < end; k++) {
    float v = x[srck[k]] * wlv + xd * wrv;
    v = v > 0.0f ? v : 0.2f * v;
    float e = av * v;
#pragma unroll
    for (int off = 32; off; off >>= 1) e += __shfl_xor(e, off);
    if (lane == 0) ework[k] = e;
    m = fmaxf(m, e);
  }
  __syncthreads();
  float sum = 0.0f, agg = 0.0f;
  for (int k = beg + lane; k < end; k += 64) {
    float p = expf(ework[k] - m);
    sum += p;
    agg += p * x[srck[k]];
  }
#pragma unroll
  for (int off = 32; off; off >>= 1) {
    sum += __shfl_xor(sum, off);
    agg += __shfl_xor(agg, off);
  }
  float o = agg / (sum + 1e-16f) * wlv + bias[lane];
  out[(size_t)node * 64 + lane] = o > 0.0f ? o : expf(o) - 1.0f;
}

// ---------------- CSR per-node logits + softmax ----------------
template <int FO, int STR, typename XT>
__global__ void k_logits_csr(const XT* __restrict__ X, const float* __restrict__ att,
                             const int* __restrict__ rowptr, const int* __restrict__ srck,
                             float* __restrict__ pk, float* __restrict__ ssum) {
  int node = blockIdx.x * 4 + (threadIdx.x >> 6);
  int lane = threadIdx.x & 63;
  constexpr int NV = FO / 64;
  float xr[NV], at[NV];
  if constexpr (sizeof(XT) == 2) {
    const short* xrp = (const short*)X + (size_t)node * STR + FO;
#pragma unroll
    for (int j = 0; j < FO / 512; j++) {
      short8v v = *(const short8v*)(xrp + j * 512 + lane * 8);
      f32x4 a0 = *(const f32x4*)(att + j * 512 + lane * 8);
      f32x4 a1 = *(const f32x4*)(att + j * 512 + lane * 8 + 4);
#pragma unroll
      for (int t = 0; t < 8; t++) {
        xr[j * 8 + t] = bfs2f(v[t]);
        at[j * 8 + t] = t < 4 ? a0[t] : a1[t - 4];
      }
    }
  } else {
    const float* xrp = (const float*)X + (size_t)node * STR + FO;
#pragma unroll
    for (int j = 0; j < FO / 256; j++) {
      f32x4 v = *(const f32x4*)(xrp + j * 256 + lane * 4);
      f32x4 a = *(const f32x4*)(att + j * 256 + lane * 4);
#pragma unroll
      for (int t = 0; t < 4; t++) {
        xr[j * 4 + t] = v[t];
        at[j * 4 + t] = a[t];
      }
    }
  }
  int beg = rowptr[node], end = rowptr[node + 1];
  float m = -INFINITY;
  for (int k = beg; k < end; k++) {
    int s = srck[k];
    float acc = 0.0f;
    if constexpr (sizeof(XT) == 2) {
      const short* xlp = (const short*)X + (size_t)s * STR;
#pragma unroll
      for (int j = 0; j < FO / 512; j++) {
        short8v v = *(const short8v*)(xlp + j * 512 + lane * 8);
#pragma unroll
        for (int t = 0; t < 8; t++) {
          float u = bfs2f(v[t]) + xr[j * 8 + t];
          u = u > 0.0f ? u : 0.2f * u;
          acc += at[j * 8 + t] * u;
        }
      }
    } else {
      const float* xlp = (const float*)X + (size_t)s * STR;
#pragma unroll
      for (int j = 0; j < FO / 256; j++) {
        f32x4 v = *(const f32x4*)(xlp + j * 256 + lane * 4);
#pragma unroll
        for (int t = 0; t < 4; t++) {
          float u = v[t] + xr[j * 4 + t];
          u = u > 0.0f ? u : 0.2f * u;
          acc += at[j * 4 + t] * u;
        }
      }
    }
#pragma unroll
    for (int off = 32; off; off >>= 1) acc += __shfl_xor(acc, off);
    if (lane == 0) pk[k] = acc;
    m = fmaxf(m, acc);
  }
  __syncthreads();
  float sum = 0.0f;
  for (int k = beg + lane; k < end; k += 64) {
    float p = expf(pk[k] - m);
    pk[k] = p;
    sum += p;
  }
#pragma unroll
  for (int off = 32; off; off >>= 1) sum += __shfl_xor(sum, off);
  if (lane == 0) ssum[node] = sum;
}

// ---------------- gather-aggregation ----------------
template <int MODE, int SSTR, int OSTR>
__global__ void k_agg512(const float* __restrict__ Xsrc, const float* __restrict__ pk,
                         const float* __restrict__ ssum, const int* __restrict__ rowptr,
                         const int* __restrict__ srck, const float* __restrict__ normk,
                         const float* __restrict__ xwrb, const float* __restrict__ bias,
                         float* __restrict__ out) {
  int wave = threadIdx.x >> 6;
  int node = blockIdx.x * 2 + (wave >> 1);
  int lane = threadIdx.x & 63;
  int c0 = (wave & 1) * 256 + lane * 4;
  f32x4 acc = {};
  int beg = rowptr[node], end = rowptr[node + 1];
  float inv = (MODE == 0) ? 1.0f / (ssum[node] + 1e-16f) : 1.0f;
  for (int k = beg; k < end; k++) {
    int s = srck[k];
    float w = (MODE == 0) ? pk[k] * inv : normk[k];
    f32x4 v = *(const f32x4*)(Xsrc + (size_t)s * SSTR + c0);
#pragma unroll
    for (int t = 0; t < 4; t++) acc[t] += w * v[t];
  }
  if constexpr (MODE == 1) {
    f32x4 xv = *(const f32x4*)(xwrb + (size_t)node * SSTR + 512 + c0);
#pragma unroll
    for (int t = 0; t < 4; t++) acc[t] = fmaxf(acc[t] + xv[t] + bias[c0 + t], 0.0f);
  }
  *(f32x4*)(out + (size_t)node * OSTR + c0) = acc;
}

template <int MODE, int SSTR, int XOFF>
__global__ void k_agg64(const float* __restrict__ Xsrc, const float* __restrict__ pk,
                        const float* __restrict__ ssum, const int* __restrict__ rowptr,
                        const int* __restrict__ srck, const float* __restrict__ normk,
                        const float* __restrict__ xwrb, const float* __restrict__ bias,
                        float* __restrict__ out) {
  int node = blockIdx.x * (blockDim.x >> 6) + (threadIdx.x >> 6);
  if (node >= NN) return;
  int lane = threadIdx.x & 63;
  int cg = lane & 15, eg = lane >> 4;
  int c0 = cg * 4;
  f32x4 acc = {};
  int beg = rowptr[node], end = rowptr[node + 1];
  float inv = (MODE == 0) ? 1.0f / (ssum[node] + 1e-16f) : 1.0f;
  for (int k = beg + eg; k < end; k += 4) {
    int s = srck[k];
    float w = (MODE == 0) ? pk[k] * inv : normk[k];
    f32x4 v = *(const f32x4*)(Xsrc + (size_t)s * SSTR + c0);
#pragma unroll
    for (int t = 0; t < 4; t++) acc[t] += w * v[t];
  }
#pragma unroll
  for (int t = 0; t < 4; t++) {
    acc[t] += __shfl_xor(acc[t], 16);
    acc[t] += __shfl_xor(acc[t], 32);
  }
  if (eg == 0) {
    if constexpr (MODE == 1) {
      f32x4 xv = *(const f32x4*)(xwrb + (size_t)node * SSTR + XOFF + c0);
#pragma unroll
      for (int t = 0; t < 4; t++) acc[t] = fmaxf(acc[t] + xv[t] + bias[c0 + t], 0.0f);
    }
    *(f32x4*)(out + (size_t)node * 64 + c0) = acc;
  }
}

// ---------------- GraphNorm (vectorized) ----------------
template <typename T, int VEC>
__global__ void k_gn_stats_v(const T* __restrict__ x, const int* __restrict__ R, int C,
                             float* __restrict__ s1, float* __restrict__ s2) {
  int g = blockIdx.x;
  int c0 = (blockIdx.y * blockDim.x + threadIdx.x) * VEC;
  if (c0 >= C) return;
  int beg = R[g], end = R[g + 1];
  float a[VEC] = {}, b[VEC] = {};
  for (int n = beg; n < end; n++) {
    const T* p = x + (size_t)n * C + c0;
    float v[VEC];
    if constexpr (sizeof(T) == 2) {
      short8v h = *(const short8v*)p;
#pragma unroll
      for (int t = 0; t < VEC; t++) v[t] = bfs2f(h[t]);
    } else {
      f32x4 h = *(const f32x4*)p;
#pragma unroll
      for (int t = 0; t < VEC; t++) v[t] = h[t];
    }
#pragma unroll
    for (int t = 0; t < VEC; t++) {
      a[t] += v[t];
      b[t] += v[t] * v[t];
    }
  }
#pragma unroll
  for (int t = 0; t < VEC; t++) {
    s1[g * C + c0 + t] = a[t];
    s2[g * C + c0 + t] = b[t];
  }
}

// EMIT: 0 = in-place only; 2 = in-place + hi bf16 plane (row-major [.][C])
template <typename T, int VEC, int EMIT>
__global__ void k_gn_apply_v(T* __restrict__ x, const int* __restrict__ batch,
                             const float* __restrict__ cnt, const float* __restrict__ s1,
                             const float* __restrict__ s2, const float* __restrict__ w,
                             const float* __restrict__ b, const float* __restrict__ ms, int C,
                             int total_vec, short* __restrict__ hip) {
  int i = blockIdx.x * blockDim.x + threadIdx.x;
  if (i >= total_vec) return;
  int cpv = C / VEC;
  int n = i / cpv, c0 = (i % cpv) * VEC;
  int g = batch[n];
  float ct = cnt[g];
  T* p = x + (size_t)n * C + c0;
  float v[VEC];
  if constexpr (sizeof(T) == 2) {
    short8v h = *(const short8v*)p;
#pragma unroll
    for (int t = 0; t < VEC; t++) v[t] = bfs2f(h[t]);
  } else {
    f32x4 h = *(const f32x4*)p;
#pragma unroll
    for (int t = 0; t < VEC; t++) v[t] = h[t];
  }
#pragma unroll
  for (int t = 0; t < VEC; t++) {
    int cc = c0 + t;
    float mean = s1[g * C + cc] / ct;
    float mm = mean * ms[cc];
    float var = s2[g * C + cc] / ct - 2.0f * mm * mean + mm * mm;
    v[t] = (v[t] - mm) * (1.0f / sqrtf(var + 1e-5f)) * w[cc] + b[cc];
  }
  if constexpr (sizeof(T) == 2) {
    short8v h;
#pragma unroll
    for (int t = 0; t < VEC; t++) h[t] = bfbits(v[t]);
    *(short8v*)p = h;
  } else {
    f32x4 h;
#pragma unroll
    for (int t = 0; t < VEC; t++) h[t] = v[t];
    *(f32x4*)p = h;
  }
  if constexpr (EMIT == 2) {
    typedef __attribute__((ext_vector_type(4))) short short4v;
    short4v hh;
#pragma unroll
    for (int t = 0; t < VEC; t++) hh[t] = bfbits(v[t]);
    *(short4v*)(hip + (size_t)n * C + c0) = hh;
  }
}

// ---------------- pooling + final linear ----------------
__global__ void k_pool(const float* __restrict__ h, const int* __restrict__ R,
                       const float* __restrict__ cnt, const float* __restrict__ lw,
                       const float* __restrict__ lb, float* __restrict__ out) {
  int g = blockIdx.x;
  int c = threadIdx.x;  // 64
  int beg = R[g], end = R[g + 1];
  float mx = -INFINITY, sm = 0.0f;
  for (int n = beg; n < end; n++) {
    float v = h[(size_t)n * 64 + c];
    mx = fmaxf(mx, v);
    sm += v;
  }
  __shared__ float feat[192];
  feat[c] = mx;
  feat[64 + c] = sm / cnt[g];
  feat[128 + c] = sm;
  __syncthreads();
  if (c < 2) {
    float acc = lb[c];
    for (int j = 0; j < 192; j++) acc += feat[j] * lw[j * 2 + c];
    out[g * 2 + c] = acc;
  }
}

// ---------------- launch ----------------

extern "C" void kernel_launch(void* const* d_in, const int* in_sizes, int n_in,
                              void* d_out, int out_size, void* d_ws, size_t ws_size,
                              hipStream_t stream) {
  const float* x = (const float*)d_in[0];
  const int* ei = (const int*)d_in[1];
  const int* batch = (const int*)d_in[2];
  const float* g1wl = (const float*)d_in[3];
  const float* g1wr = (const float*)d_in[4];
  const float* g1att = (const float*)d_in[5];
  const float* g1b = (const float*)d_in[6];
  const float* g2wl = (const float*)d_in[7];
  const float* g2wr = (const float*)d_in[8];
  const float* g2att = (const float*)d_in[9];
  const float* g2b = (const float*)d_in[10];
  const float* g3wl = (const float*)d_in[11];
  const float* g3wr = (const float*)d_in[12];
  const float* g3att = (const float*)d_in[13];
  const float* g3b = (const float*)d_in[14];
  const float* gn1w = (const float*)d_in[15];
  const float* gn1b = (const float*)d_in[16];
  const float* gn1ms = (const float*)d_in[17];
  const float* gn2w = (const float*)d_in[18];
  const float* gn2b = (const float*)d_in[19];
  const float* gn2ms = (const float*)d_in[20];
  const float* gn3w = (const float*)d_in[21];
  const float* gn3b = (const float*)d_in[22];
  const float* gn3ms = (const float*)d_in[23];
  const float* gn4w = (const float*)d_in[24];
  const float* gn4b = (const float*)d_in[25];
  const float* gn4ms = (const float*)d_in[26];
  const float* gn5w = (const float*)d_in[27];
  const float* gn5b = (const float*)d_in[28];
  const float* gn5ms = (const float*)d_in[29];
  const float* a1wi = (const float*)d_in[30];
  const float* a1wr = (const float*)d_in[31];
  const float* a1b = (const float*)d_in[32];
  const float* a2wi = (const float*)d_in[33];
  const float* a2wr = (const float*)d_in[34];
  const float* a2b = (const float*)d_in[35];
  const float* linw = (const float*)d_in[36];
  const float* linb = (const float*)d_in[37];
  const int* srcp = ei;
  const int* dstp = ei + NE;
  float* out = (float*)d_out;

  float* ws = (float*)d_ws;
  size_t o = 0;
  auto alloc = [&](size_t nfloats) { float* p = ws + o; o += nfloats; return p; };
  float* BIG0f = alloc((size_t)NN * 1024);  // 64 MB
  float* BIG1f = alloc((size_t)NN * 1024);  // 64 MB
  float* B0 = alloc((size_t)NN * 512);      // 32 MB
  float* B1 = alloc((size_t)NN * 512);      // 32 MB
  float* h1 = alloc((size_t)NN * 64);
  float* aggS = alloc((size_t)NN * 64);
  float* S0 = alloc((size_t)NN * 64);  // [t2|xwr2] spans S0+S1
  float* S1 = alloc((size_t)NN * 64);
  float* S2 = alloc((size_t)NN * 64);  // h5
  float* pk = alloc(NESL);
  float* normk = alloc(NESL);
  float* ssum = alloc(NN);
  float* dis = alloc(NN);
  float* cnt = alloc(NG);
  float* s1 = alloc(NG * 2048);
  float* s2 = alloc(NG * 2048);
  short* WThi = (short*)alloc((size_t)4096 * 512 / 2);  // 4 MB packed tiles
  short* WTlo = (short*)alloc((size_t)4096 * 512 / 2);
  int* deg = (int*)alloc(NN);
  int* rowptr = (int*)alloc(NN + 1);
  int* fill = (int*)alloc(NN);
  int* srck = (int*)alloc(NESL);
  int* R = (int*)alloc(72);

  bf16* XLR3 = (bf16*)BIG0f;  // [NN][4096] bf16 (spans BIG0f+BIG1f)
  bf16* h3 = (bf16*)BIG0f;    // [NN][2048] bf16 (after XLR3 dead)
  float* h4 = BIG1f;          // [NN][512] f32 (after XLR3 dead)
  float* XLR2 = B0;           // [NN][1024] f32 (spans B0+B1)
  float* h2 = B0;             // [NN][512] f32
  short* h2hi = (short*)B1;   // [NN][512] bf16 hi plane (before agg2)
  float* agg2 = B1;           // [NN][512] f32 (overwrites h2hi after it's dead)
  float* TXW1 = B0;           // [t1|xwr1] [NN][1024] f32
  float* TXW2 = S0;           // [t2|xwr2] [NN][128] f32

  // ---- preprocessing ----
  k_zero2<<<NN / 256, 256, 0, stream>>>(deg, fill, NN);
  k_ranges<<<1, 128, 0, stream>>>(batch, R, cnt);
  k_deg<<<NE / 256, 256, 0, stream>>>(dstp, deg);
  k_scan<<<1, 1024, 0, stream>>>(deg, rowptr);
  k_dis<<<NN / 256, 256, 0, stream>>>(deg, dis);
  k_fill<<<(NESL + 255) / 256, 256, 0, stream>>>(srcp, dstp, rowptr, dis, fill, srck, normk);

  // ---- GAT1 (1 -> 64, rank-1, fused) ----
  k_gat1_csr<<<NN / 4, 256, 0, stream>>>(x, g1wl, g1wr, g1att, rowptr, srck, pk, g1b, h1);
  k_gn_stats_v<float, 4><<<dim3(NG, 1), 16, 0, stream>>>(h1, R, 64, s1, s2);
  k_gn_apply_v<float, 4, 0><<<NN * 16 / 256, 256, 0, stream>>>(h1, batch, cnt, s1, s2, gn1w,
                                                               gn1b, gn1ms, 64, NN * 16, nullptr);

  // ---- GAT2 (64 -> 512) ----
  k_wsplit_pk<<<(512 * 64 + 255) / 256, 256, 0, stream>>>(g2wl, WThi, WTlo, 64, 512, 0);
  k_wsplit_pk<<<(512 * 64 + 255) / 256, 256, 0, stream>>>(g2wr, WThi, WTlo, 64, 512, 512);
  gemm_mfma_s<0, 0><<<dim3(8, 128), 256, 0, stream>>>(h1, WThi, WTlo, XLR2, nullptr, NN, 1024, 64);
  k_logits_csr<512, 1024, float><<<NN / 4, 256, 0, stream>>>(XLR2, g2att, rowptr, srck, pk, ssum);
  k_agg64<0, 64, 0><<<NN / 4, 256, 0, stream>>>(h1, pk, ssum, rowptr, srck, normk, nullptr,
                                                nullptr, aggS);
  gemm_mfma_s<0, 1><<<dim3(4, 128), 256, 0, stream>>>(aggS, WThi, WTlo, h2, g2b, NN, 512, 64);
  k_gn_stats_v<float, 4><<<dim3(NG, 1), 128, 0, stream>>>(h2, R, 512, s1, s2);
  k_gn_apply_v<float, 4, 2><<<NN * 128 / 256, 256, 0, stream>>>(h2, batch, cnt, s1, s2, gn2w,
                                                                gn2b, gn2ms, 512, NN * 128, h2hi);

  // ---- GAT3 (512 -> 2048): XLR via pipelined bf16-plane GEMM ----
  k_wsplit_pk<<<(2048 * 512 + 255) / 256, 256, 0, stream>>>(g3wl, WThi, WTlo, 512, 2048, 0);
  k_wsplit_pk<<<(2048 * 512 + 255) / 256, 256, 0, stream>>>(g3wr, WThi, WTlo, 512, 2048, 2048);
  gemm_mfma_p<1, 0><<<dim3(32, 128), 256, 0, stream>>>(h2hi, WThi, WTlo, XLR3, nullptr, NN,
                                                       4096, 512);
  k_logits_csr<2048, 4096, bf16><<<NN / 4, 256, 0, stream>>>(XLR3, g3att, rowptr, srck, pk, ssum);
  k_agg512<0, 512, 512><<<NN / 2, 256, 0, stream>>>(h2, pk, ssum, rowptr, srck, normk, nullptr,
                                                    nullptr, agg2);
  gemm_mfma_s<1, 1><<<dim3(16, 128), 256, 0, stream>>>(agg2, WThi, WTlo, h3, g3b, NN, 2048, 512);
  k_gn_stats_v<bf16, 8><<<dim3(NG, 1), 256, 0, stream>>>(h3, R, 2048, s1, s2);
  k_gn_apply_v<bf16, 8, 0><<<NN * 256 / 256, 256, 0, stream>>>(h3, batch, cnt, s1, s2, gn3w,
                                                               gn3b, gn3ms, 2048, NN * 256,
                                                               nullptr);

  // ---- ARMA1 (2048 -> 512): pipelined bf16-plane GEMM (A = h3) ----
  k_wsplit_pk<<<(512 * 2048 + 255) / 256, 256, 0, stream>>>(a1wi, WThi, WTlo, 2048, 512, 0);
  k_wsplit_pk<<<(512 * 2048 + 255) / 256, 256, 0, stream>>>(a1wr, WThi, WTlo, 2048, 512, 512);
  gemm_mfma_p<0, 0><<<dim3(8, 128), 256, 0, stream>>>((const short*)h3, WThi, WTlo, TXW1,
                                                      nullptr, NN, 1024, 2048);
  k_agg512<1, 1024, 512><<<NN / 2, 256, 0, stream>>>(TXW1, pk, nullptr, rowptr, srck, normk,
                                                     TXW1, a1b, h4);
  k_gn_stats_v<float, 4><<<dim3(NG, 1), 128, 0, stream>>>(h4, R, 512, s1, s2);
  k_gn_apply_v<float, 4, 0><<<NN * 128 / 256, 256, 0, stream>>>(h4, batch, cnt, s1, s2, gn4w,
                                                                gn4b, gn4ms, 512, NN * 128,
                                                                nullptr);

  // ---- ARMA2 (512 -> 64) ----
  k_wsplit_pk<<<(64 * 512 + 255) / 256, 256, 0, stream>>>(a2wi, WThi, WTlo, 512, 64, 0);
  k_wsplit_pk<<<(64 * 512 + 255) / 256, 256, 0, stream>>>(a2wr, WThi, WTlo, 512, 64, 64);
  gemm_mfma_s<0, 0><<<dim3(1, 128), 256, 0, stream>>>(h4, WThi, WTlo, TXW2, nullptr, NN, 128, 512);
  k_agg64<1, 128, 64><<<NN / 4, 256, 0, stream>>>(TXW2, pk, nullptr, rowptr, srck, normk, TXW2,
                                                  a2b, S2);
  k_gn_stats_v<float, 4><<<dim3(NG, 1), 16, 0, stream>>>(S2, R, 64, s1, s2);
  k_gn_apply_v<float, 4, 0><<<NN * 16 / 256, 256, 0, stream>>>(S2, batch, cnt, s1, s2, gn5w,
                                                               gn5b, gn5ms, 64, NN * 16, nullptr);

  // ---- pooling + linear ----
  k_pool<<<NG, 64, 0, stream>>>(S2, R, cnt, linw, linb, out);
}